// Round 1
// baseline (2673.429 us; speedup 1.0000x reference)
//
#include <hip/hip_runtime.h>
#include <hip/hip_bf16.h>

#define NIN 6
#define HIDN 64
#define NHEAD 4

// ---- order-preserving float<->uint key for atomicMax on floats ----
__device__ __forceinline__ unsigned fkey(float f) {
    unsigned u = __float_as_uint(f);
    return (u & 0x80000000u) ? ~u : (u | 0x80000000u);
}
__device__ __forceinline__ float funkey(unsigned k) {
    return (k & 0x80000000u) ? __uint_as_float(k ^ 0x80000000u) : __uint_as_float(~k);
}

// ---- node encoder: wave per node. h = relu(x@w1+b1)@w2+b2 ----
__global__ __launch_bounds__(256) void encode_kernel(
    const float* __restrict__ x,
    const float* __restrict__ w1, const float* __restrict__ b1,
    const float* __restrict__ w2, const float* __restrict__ b2,
    float* __restrict__ h, int N) {
    int t = blockIdx.x * blockDim.x + threadIdx.x;
    int n = t >> 6, j = t & 63;
    if (n >= N) return;
    float acc = b1[j];
#pragma unroll
    for (int i = 0; i < NIN; i++) acc += x[n * NIN + i] * w1[i * HIDN + j];
    float hid = acc > 0.f ? acc : 0.f;
    float acc2 = b2[j];
#pragma unroll
    for (int k = 0; k < HIDN; k++) acc2 += __shfl(hid, k) * w2[k * HIDN + j];
    h[n * HIDN + j] = acc2;
}

// ---- tiny per-layer edge-attention constants:
// a_e[i,h] = edge_attr[i]*c1[l,h] + c0[l,h]
__global__ void consts_kernel(const float* __restrict__ w_ee, const float* __restrict__ b_ee,
                              const float* __restrict__ w_eg, const float* __restrict__ att_edge,
                              float* __restrict__ c1, float* __restrict__ c0) {
    int t = threadIdx.x;
    if (t >= 12) return;
    int l = t >> 2, hh = t & 3;
    float s1 = 0.f, s0 = 0.f;
    for (int j = 0; j < HIDN; j++) {
        float wj = 0.f;
        for (int d = 0; d < 16; d++)
            wj += w_eg[l * 4096 + j * 64 + hh * 16 + d] * att_edge[l * 64 + hh * 16 + d];
        s1 += w_ee[j] * wj;
        s0 += b_ee[j] * wj;
    }
    c1[l * 4 + hh] = s1;
    c0[l * 4 + hh] = s0;
}

// ---- per-layer node transform: hw = h@w_gat[l]; a_s, a_d head-dots ----
__global__ __launch_bounds__(256) void gat_node_kernel(
    const float* __restrict__ h, const float* __restrict__ wg,
    const float* __restrict__ att_s, const float* __restrict__ att_d,
    float* __restrict__ hw, float* __restrict__ a_s, float* __restrict__ a_d, int N) {
    int t = blockIdx.x * blockDim.x + threadIdx.x;
    int n = t >> 6, j = t & 63;
    if (n >= N) return;
    float hv = h[n * HIDN + j];
    float acc = 0.f;
#pragma unroll
    for (int k = 0; k < HIDN; k++) acc += __shfl(hv, k) * wg[k * HIDN + j];
    hw[n * HIDN + j] = acc;
    // att_s/att_d laid out [H,D] = 64 contiguous, index j directly
    float ts = acc * att_s[j];
    float td = acc * att_d[j];
#pragma unroll
    for (int o = 8; o > 0; o >>= 1) {
        ts += __shfl_xor(ts, o);
        td += __shfl_xor(td, o);
    }
    if ((j & 15) == 0) {
        int hh = j >> 4;
        a_s[n * NHEAD + hh] = ts;
        a_d[n * NHEAD + hh] = td;
    }
}

// ---- edge pass 1: score = leaky_relu(a_s[src]+a_d[dst]+a_e), atomic segment max ----
__global__ __launch_bounds__(256) void edge_score_kernel(
    const int* __restrict__ ei, const float* __restrict__ eattr,
    const float* __restrict__ a_s, const float* __restrict__ a_d,
    const float* __restrict__ c1, const float* __restrict__ c0,
    float* __restrict__ score, unsigned* __restrict__ smax, int E) {
    int e = blockIdx.x * blockDim.x + threadIdx.x;
    if (e >= E) return;
    int s = ei[e], d = ei[E + e];
    float ea = eattr[e];
    float4 as4 = *(const float4*)(a_s + (size_t)s * 4);
    float4 ad4 = *(const float4*)(a_d + (size_t)d * 4);
    float sc[4];
    sc[0] = as4.x + ad4.x + ea * c1[0] + c0[0];
    sc[1] = as4.y + ad4.y + ea * c1[1] + c0[1];
    sc[2] = as4.z + ad4.z + ea * c1[2] + c0[2];
    sc[3] = as4.w + ad4.w + ea * c1[3] + c0[3];
#pragma unroll
    for (int hh = 0; hh < 4; hh++) {
        sc[hh] = sc[hh] >= 0.f ? sc[hh] : 0.2f * sc[hh];
        atomicMax(&smax[(size_t)d * 4 + hh], fkey(sc[hh]));
    }
    *(float4*)(score + (size_t)e * 4) = make_float4(sc[0], sc[1], sc[2], sc[3]);
}

// ---- edge pass 2: ex = exp(score - smax[dst]); den[dst] += ex ----
__global__ __launch_bounds__(256) void edge_exp_kernel(
    const int* __restrict__ ei, const unsigned* __restrict__ smax,
    float* __restrict__ score, float* __restrict__ den, int E) {
    int e = blockIdx.x * blockDim.x + threadIdx.x;
    if (e >= E) return;
    int d = ei[E + e];
    float4 sc = *(const float4*)(score + (size_t)e * 4);
    uint4 k4 = *(const uint4*)(smax + (size_t)d * 4);
    float ex0 = __expf(sc.x - funkey(k4.x));
    float ex1 = __expf(sc.y - funkey(k4.y));
    float ex2 = __expf(sc.z - funkey(k4.z));
    float ex3 = __expf(sc.w - funkey(k4.w));
    *(float4*)(score + (size_t)e * 4) = make_float4(ex0, ex1, ex2, ex3);
    atomicAdd(&den[(size_t)d * 4 + 0], ex0);
    atomicAdd(&den[(size_t)d * 4 + 1], ex1);
    atomicAdd(&den[(size_t)d * 4 + 2], ex2);
    atomicAdd(&den[(size_t)d * 4 + 3], ex3);
}

// ---- edge pass 3: agg[dst] += alpha * hw[src]; wave per edge, lane per channel ----
__global__ __launch_bounds__(256) void edge_scatter_kernel(
    const int* __restrict__ ei, const float* __restrict__ ex,
    const float* __restrict__ den, const float* __restrict__ hw,
    float* __restrict__ agg, int E) {
    int t = blockIdx.x * blockDim.x + threadIdx.x;
    int e = t >> 6, j = t & 63;
    if (e >= E) return;
    int s = ei[e], d = ei[E + e];
    int hh = j >> 4;
    float alpha = ex[(size_t)e * 4 + hh] / (den[(size_t)d * 4 + hh] + 1e-16f);
    atomicAdd(&agg[(size_t)d * HIDN + j], alpha * hw[(size_t)s * HIDN + j]);
}

// ---- epilogue per layer: h = LN(h + elu(agg + b_gat)) ----
__global__ __launch_bounds__(256) void update_ln_kernel(
    float* __restrict__ h, const float* __restrict__ agg,
    const float* __restrict__ bg, const float* __restrict__ g,
    const float* __restrict__ b, int N) {
    int t = blockIdx.x * blockDim.x + threadIdx.x;
    int n = t >> 6, j = t & 63;
    if (n >= N) return;
    float a = agg[(size_t)n * HIDN + j] + bg[j];
    float el = a > 0.f ? a : (__expf(a) - 1.f);
    float v = h[(size_t)n * HIDN + j] + el;
    float s = v, sq = v * v;
#pragma unroll
    for (int o = 32; o > 0; o >>= 1) {
        s += __shfl_xor(s, o);
        sq += __shfl_xor(sq, o);
    }
    float m = s * (1.f / 64.f);
    float var = sq * (1.f / 64.f) - m * m;
    float r = rsqrtf(var + 1e-5f);
    h[(size_t)n * HIDN + j] = (v - m) * r * g[j] + b[j];
}

// ---- final projection: out = h @ w_out + b_out ----
__global__ __launch_bounds__(256) void out_kernel(
    const float* __restrict__ h, const float* __restrict__ w,
    const float* __restrict__ b, float* __restrict__ out, int N) {
    int t = blockIdx.x * blockDim.x + threadIdx.x;
    int n = t >> 6, j = t & 63;
    if (n >= N) return;
    float hv = h[(size_t)n * HIDN + j];
    float acc = b[j];
#pragma unroll
    for (int k = 0; k < HIDN; k++) acc += __shfl(hv, k) * w[k * HIDN + j];
    out[(size_t)n * HIDN + j] = acc;
}

extern "C" void kernel_launch(void* const* d_in, const int* in_sizes, int n_in,
                              void* d_out, int out_size, void* d_ws, size_t ws_size,
                              hipStream_t stream) {
    const float* x      = (const float*)d_in[0];
    const int*   ei     = (const int*)d_in[1];
    const float* eattr  = (const float*)d_in[2];
    const float* w_ne1  = (const float*)d_in[3];
    const float* b_ne1  = (const float*)d_in[4];
    const float* w_ne2  = (const float*)d_in[5];
    const float* b_ne2  = (const float*)d_in[6];
    const float* w_ee   = (const float*)d_in[7];
    const float* b_ee   = (const float*)d_in[8];
    const float* w_gat  = (const float*)d_in[9];
    const float* w_eg   = (const float*)d_in[10];
    const float* att_src= (const float*)d_in[11];
    const float* att_dst= (const float*)d_in[12];
    const float* att_edge=(const float*)d_in[13];
    const float* b_gat  = (const float*)d_in[14];
    const float* ln_g   = (const float*)d_in[15];
    const float* ln_b   = (const float*)d_in[16];
    const float* w_out  = (const float*)d_in[17];
    const float* b_out  = (const float*)d_in[18];

    const int N = in_sizes[0] / NIN;
    const int E = in_sizes[2];
    const int L = 3;

    // workspace layout (floats)
    float* ws   = (float*)d_ws;
    float* h    = ws;                       // N*64
    float* hw   = h + (size_t)N * 64;       // N*64
    float* a_s  = hw + (size_t)N * 64;      // N*4
    float* a_d  = a_s + (size_t)N * 4;      // N*4
    unsigned* smax = (unsigned*)(a_d + (size_t)N * 4);  // N*4
    float* den  = (float*)(smax + (size_t)N * 4);       // N*4
    float* score= den + (size_t)N * 4;      // E*4 (scores, then exp)
    float* agg  = score + (size_t)E * 4;    // N*64
    float* c1   = agg + (size_t)N * 64;     // L*4
    float* c0   = c1 + 12;                  // L*4

    dim3 blk(256);
    int nodeWaveBlocks = (N * 64 + 255) / 256;
    int edgeBlocks = (E + 255) / 256;
    int scatterBlocks = (int)(((long long)E * 64 + 255) / 256);

    encode_kernel<<<nodeWaveBlocks, blk, 0, stream>>>(x, w_ne1, b_ne1, w_ne2, b_ne2, h, N);
    consts_kernel<<<1, 64, 0, stream>>>(w_ee, b_ee, w_eg, att_edge, c1, c0);

    for (int l = 0; l < L; l++) {
        hipMemsetAsync(smax, 0, (size_t)N * 4 * sizeof(unsigned), stream);
        hipMemsetAsync(den, 0, (size_t)N * 4 * sizeof(float), stream);
        hipMemsetAsync(agg, 0, (size_t)N * 64 * sizeof(float), stream);
        gat_node_kernel<<<nodeWaveBlocks, blk, 0, stream>>>(
            h, w_gat + (size_t)l * 4096, att_src + l * 64, att_dst + l * 64,
            hw, a_s, a_d, N);
        edge_score_kernel<<<edgeBlocks, blk, 0, stream>>>(
            ei, eattr, a_s, a_d, c1 + l * 4, c0 + l * 4, score, smax, E);
        edge_exp_kernel<<<edgeBlocks, blk, 0, stream>>>(ei, smax, score, den, E);
        edge_scatter_kernel<<<scatterBlocks, blk, 0, stream>>>(ei, score, den, hw, agg, E);
        update_ln_kernel<<<nodeWaveBlocks, blk, 0, stream>>>(
            h, agg, b_gat + l * 64, ln_g + l * 64, ln_b + l * 64, N);
    }
    out_kernel<<<nodeWaveBlocks, blk, 0, stream>>>(h, w_out, b_out, (float*)d_out, N);
}

// Round 2
// 1022.537 us; speedup vs baseline: 2.6145x; 2.6145x over previous
//
#include <hip/hip_runtime.h>
#include <hip/hip_bf16.h>

#define NIN 6
#define HIDN 64
#define NHEAD 4

// ================= node encoder: wave per node. h = relu(x@w1+b1)@w2+b2 =====
__global__ __launch_bounds__(256) void encode_kernel(
    const float* __restrict__ x,
    const float* __restrict__ w1, const float* __restrict__ b1,
    const float* __restrict__ w2, const float* __restrict__ b2,
    float* __restrict__ h, int N) {
    int t = blockIdx.x * blockDim.x + threadIdx.x;
    int n = t >> 6, j = t & 63;
    if (n >= N) return;
    float acc = b1[j];
#pragma unroll
    for (int i = 0; i < NIN; i++) acc += x[n * NIN + i] * w1[i * HIDN + j];
    float hid = acc > 0.f ? acc : 0.f;
    float acc2 = b2[j];
#pragma unroll
    for (int k = 0; k < HIDN; k++) acc2 += __shfl(hid, k) * w2[k * HIDN + j];
    h[n * HIDN + j] = acc2;
}

// ====== tiny per-layer edge-attn constants: a_e[i,h] = eattr[i]*c1 + c0 =====
__global__ void consts_kernel(const float* __restrict__ w_ee, const float* __restrict__ b_ee,
                              const float* __restrict__ w_eg, const float* __restrict__ att_edge,
                              float* __restrict__ c1, float* __restrict__ c0) {
    int t = threadIdx.x;
    if (t >= 12) return;
    int l = t >> 2, hh = t & 3;
    float s1 = 0.f, s0 = 0.f;
    for (int j = 0; j < HIDN; j++) {
        float wj = 0.f;
        for (int d = 0; d < 16; d++)
            wj += w_eg[l * 4096 + j * 64 + hh * 16 + d] * att_edge[l * 64 + hh * 16 + d];
        s1 += w_ee[j] * wj;
        s0 += b_ee[j] * wj;
    }
    c1[l * 4 + hh] = s1;
    c0[l * 4 + hh] = s0;
}

// ================= CSR build: histogram -> scan -> scatter ==================
__global__ __launch_bounds__(256) void hist_kernel(const int* __restrict__ ei,
                                                   unsigned* __restrict__ deg, int E) {
    int e = blockIdx.x * 256 + threadIdx.x;
    if (e < E) atomicAdd(&deg[ei[E + e]], 1u);
}

__global__ __launch_bounds__(256) void scan1_kernel(const unsigned* __restrict__ deg,
                                                    unsigned* __restrict__ rp,
                                                    unsigned* __restrict__ bsum, int N) {
    __shared__ unsigned sm[256];
    int t = threadIdx.x, i = blockIdx.x * 256 + t;
    unsigned v = (i < N) ? deg[i] : 0u;
    sm[t] = v;
    __syncthreads();
    unsigned x = v;
    for (int o = 1; o < 256; o <<= 1) {
        unsigned add = (t >= o) ? sm[t - o] : 0u;
        __syncthreads();
        x += add; sm[t] = x;
        __syncthreads();
    }
    if (i < N) rp[i] = x - v;                 // block-local exclusive
    if (t == 255) bsum[blockIdx.x] = x;       // block total
}

__global__ void scan2_kernel(const unsigned* __restrict__ bsum,
                             unsigned* __restrict__ boff, int nb) {
    __shared__ unsigned sm[1024];
    int t = threadIdx.x;
    unsigned v = (t < nb) ? bsum[t] : 0u;
    sm[t] = v;
    __syncthreads();
    unsigned x = v;
    for (int o = 1; o < 1024; o <<= 1) {
        unsigned add = (t >= o) ? sm[t - o] : 0u;
        __syncthreads();
        x += add; sm[t] = x;
        __syncthreads();
    }
    if (t < nb) boff[t] = x - v;              // exclusive
}

__global__ __launch_bounds__(256) void scan3_kernel(unsigned* __restrict__ rp,
                                                    unsigned* __restrict__ wp,
                                                    const unsigned* __restrict__ boff,
                                                    int N, int E) {
    int i = blockIdx.x * 256 + threadIdx.x;
    if (i < N) {
        unsigned r = rp[i] + boff[blockIdx.x];
        rp[i] = r;
        wp[i] = r;
    }
    if (i == 0) rp[N] = (unsigned)E;
}

__global__ __launch_bounds__(256) void csr_scatter_kernel(
    const int* __restrict__ ei, const float* __restrict__ eattr,
    unsigned* __restrict__ wp, int* __restrict__ col, float* __restrict__ eas, int E) {
    int e = blockIdx.x * 256 + threadIdx.x;
    if (e >= E) return;
    int s = ei[e], d = ei[E + e];
    unsigned p = atomicAdd(&wp[d], 1u);
    col[p] = s;
    eas[p] = eattr[e];
}

// ========== per-layer node transform: hw = h@w_gat[l]; a_s, a_d dots ========
__global__ __launch_bounds__(256) void gat_node_kernel(
    const float* __restrict__ h, const float* __restrict__ wg,
    const float* __restrict__ att_s, const float* __restrict__ att_d,
    float* __restrict__ hw, float* __restrict__ a_s, float* __restrict__ a_d, int N) {
    int t = blockIdx.x * blockDim.x + threadIdx.x;
    int n = t >> 6, j = t & 63;
    if (n >= N) return;
    float hv = h[n * HIDN + j];
    float acc = 0.f;
#pragma unroll
    for (int k = 0; k < HIDN; k++) acc += __shfl(hv, k) * wg[k * HIDN + j];
    hw[n * HIDN + j] = acc;
    float ts = acc * att_s[j];
    float td = acc * att_d[j];
#pragma unroll
    for (int o = 8; o > 0; o >>= 1) {
        ts += __shfl_xor(ts, o);
        td += __shfl_xor(td, o);
    }
    if ((j & 15) == 0) {
        int hh = j >> 4;
        a_s[n * NHEAD + hh] = ts;
        a_d[n * NHEAD + hh] = td;
    }
}

// ===== fused per-layer edge pipeline: wave per dst node ====================
// score -> online softmax (butterfly reductions) -> weighted agg of hw[src]
// -> +b_gat, ELU, +h residual, LayerNorm -> write h. No atomics.
__global__ __launch_bounds__(256) void gat_fused_kernel(
    const unsigned* __restrict__ rp, const int* __restrict__ col,
    const float* __restrict__ eas, const float* __restrict__ hw,
    const float* __restrict__ a_s, const float* __restrict__ a_d,
    const float* __restrict__ c1, const float* __restrict__ c0,
    float* __restrict__ h, const float* __restrict__ bg,
    const float* __restrict__ g, const float* __restrict__ b, int N) {
    int t = blockIdx.x * blockDim.x + threadIdx.x;
    int n = t >> 6, j = t & 63;
    if (n >= N) return;
    int hh = j >> 4;

    unsigned beg = rp[n];
    int deg = (int)(rp[n + 1] - beg);

    float4 ad4 = *(const float4*)(a_d + (size_t)n * 4);
    float4 C1 = *(const float4*)c1;
    float4 C0 = *(const float4*)c0;

    float m0 = -1e30f, m1 = -1e30f, m2 = -1e30f, m3 = -1e30f;
    float s0 = 0.f, s1 = 0.f, s2 = 0.f, s3 = 0.f;
    float acc = 0.f;

    for (int cs = 0; cs < deg; cs += 64) {
        int i = cs + j;
        bool act = i < deg;
        int src = act ? col[beg + i] : 0;
        float ea = act ? eas[beg + i] : 0.f;
        float sc0 = -1e30f, sc1 = -1e30f, sc2 = -1e30f, sc3 = -1e30f;
        if (act) {
            float4 as4 = *(const float4*)(a_s + (size_t)src * 4);
            sc0 = as4.x + ad4.x + ea * C1.x + C0.x;
            sc1 = as4.y + ad4.y + ea * C1.y + C0.y;
            sc2 = as4.z + ad4.z + ea * C1.z + C0.z;
            sc3 = as4.w + ad4.w + ea * C1.w + C0.w;
            sc0 = sc0 >= 0.f ? sc0 : 0.2f * sc0;
            sc1 = sc1 >= 0.f ? sc1 : 0.2f * sc1;
            sc2 = sc2 >= 0.f ? sc2 : 0.2f * sc2;
            sc3 = sc3 >= 0.f ? sc3 : 0.2f * sc3;
        }
        // chunk max per head (butterfly -> all lanes)
        float x0 = sc0, x1 = sc1, x2 = sc2, x3 = sc3;
#pragma unroll
        for (int o = 32; o > 0; o >>= 1) {
            x0 = fmaxf(x0, __shfl_xor(x0, o));
            x1 = fmaxf(x1, __shfl_xor(x1, o));
            x2 = fmaxf(x2, __shfl_xor(x2, o));
            x3 = fmaxf(x3, __shfl_xor(x3, o));
        }
        float nm0 = fmaxf(m0, x0), nm1 = fmaxf(m1, x1);
        float nm2 = fmaxf(m2, x2), nm3 = fmaxf(m3, x3);
        float r0 = __expf(m0 - nm0), r1 = __expf(m1 - nm1);
        float r2 = __expf(m2 - nm2), r3 = __expf(m3 - nm3);
        m0 = nm0; m1 = nm1; m2 = nm2; m3 = nm3;

        float ex0 = act ? __expf(sc0 - nm0) : 0.f;
        float ex1 = act ? __expf(sc1 - nm1) : 0.f;
        float ex2 = act ? __expf(sc2 - nm2) : 0.f;
        float ex3 = act ? __expf(sc3 - nm3) : 0.f;
        // chunk sum per head
        float y0 = ex0, y1 = ex1, y2 = ex2, y3 = ex3;
#pragma unroll
        for (int o = 32; o > 0; o >>= 1) {
            y0 += __shfl_xor(y0, o);
            y1 += __shfl_xor(y1, o);
            y2 += __shfl_xor(y2, o);
            y3 += __shfl_xor(y3, o);
        }
        s0 = s0 * r0 + y0; s1 = s1 * r1 + y1;
        s2 = s2 * r2 + y2; s3 = s3 * r3 + y3;

        float rj = hh == 0 ? r0 : hh == 1 ? r1 : hh == 2 ? r2 : r3;
        acc *= rj;

        int cl = deg - cs; if (cl > 64) cl = 64;
        for (int i2 = 0; i2 < cl; i2++) {
            int si = __shfl(src, i2);
            float e0 = __shfl(ex0, i2), e1 = __shfl(ex1, i2);
            float e2 = __shfl(ex2, i2), e3 = __shfl(ex3, i2);
            float w = hh == 0 ? e0 : hh == 1 ? e1 : hh == 2 ? e2 : e3;
            acc += w * hw[(size_t)si * HIDN + j];
        }
    }
    float den = hh == 0 ? s0 : hh == 1 ? s1 : hh == 2 ? s2 : s3;
    float agg = acc / (den + 1e-16f);

    // epilogue: h = LN(h + elu(agg + bg))
    float a = agg + bg[j];
    float el = a > 0.f ? a : (__expf(a) - 1.f);
    float v = h[(size_t)n * HIDN + j] + el;
    float s = v, sq = v * v;
#pragma unroll
    for (int o = 32; o > 0; o >>= 1) {
        s += __shfl_xor(s, o);
        sq += __shfl_xor(sq, o);
    }
    float mean = s * (1.f / 64.f);
    float var = sq * (1.f / 64.f) - mean * mean;
    float r = rsqrtf(var + 1e-5f);
    h[(size_t)n * HIDN + j] = (v - mean) * r * g[j] + b[j];
}

// ================= final projection: out = h @ w_out + b_out ===============
__global__ __launch_bounds__(256) void out_kernel(
    const float* __restrict__ h, const float* __restrict__ w,
    const float* __restrict__ b, float* __restrict__ out, int N) {
    int t = blockIdx.x * blockDim.x + threadIdx.x;
    int n = t >> 6, j = t & 63;
    if (n >= N) return;
    float hv = h[(size_t)n * HIDN + j];
    float acc = b[j];
#pragma unroll
    for (int k = 0; k < HIDN; k++) acc += __shfl(hv, k) * w[k * HIDN + j];
    out[(size_t)n * HIDN + j] = acc;
}

extern "C" void kernel_launch(void* const* d_in, const int* in_sizes, int n_in,
                              void* d_out, int out_size, void* d_ws, size_t ws_size,
                              hipStream_t stream) {
    const float* x      = (const float*)d_in[0];
    const int*   ei     = (const int*)d_in[1];
    const float* eattr  = (const float*)d_in[2];
    const float* w_ne1  = (const float*)d_in[3];
    const float* b_ne1  = (const float*)d_in[4];
    const float* w_ne2  = (const float*)d_in[5];
    const float* b_ne2  = (const float*)d_in[6];
    const float* w_ee   = (const float*)d_in[7];
    const float* b_ee   = (const float*)d_in[8];
    const float* w_gat  = (const float*)d_in[9];
    const float* w_eg   = (const float*)d_in[10];
    const float* att_src= (const float*)d_in[11];
    const float* att_dst= (const float*)d_in[12];
    const float* att_edge=(const float*)d_in[13];
    const float* b_gat  = (const float*)d_in[14];
    const float* ln_g   = (const float*)d_in[15];
    const float* ln_b   = (const float*)d_in[16];
    const float* w_out  = (const float*)d_in[17];
    const float* b_out  = (const float*)d_in[18];

    const int N = in_sizes[0] / NIN;
    const int E = in_sizes[2];
    const int L = 3;

    // -------- workspace layout --------
    float* ws   = (float*)d_ws;
    float* h    = ws;                          // N*64
    float* hw   = h + (size_t)N * 64;          // N*64
    float* a_s  = hw + (size_t)N * 64;         // N*4
    float* a_d  = a_s + (size_t)N * 4;         // N*4
    float* c1   = a_d + (size_t)N * 4;         // 12
    float* c0   = c1 + 12;                     // 12
    float* eas  = c0 + 12;                     // E (dst-sorted edge_attr)
    int*   col  = (int*)(eas + (size_t)E);     // E (dst-sorted src)
    unsigned* deg = (unsigned*)(col + (size_t)E);   // N
    unsigned* rp  = deg + (size_t)N;                // N+1
    unsigned* wp  = rp + (size_t)N + 1;             // N
    unsigned* bsum= wp + (size_t)N;                 // <=1024
    unsigned* boff= bsum + 1024;                    // <=1024

    dim3 blk(256);
    int nodeWaveBlocks = (int)(((size_t)N * 64 + 255) / 256);
    int edgeBlocks = (E + 255) / 256;
    int nodeBlocks = (N + 255) / 256;   // scan grid, one elem per thread

    encode_kernel<<<nodeWaveBlocks, blk, 0, stream>>>(x, w_ne1, b_ne1, w_ne2, b_ne2, h, N);
    consts_kernel<<<1, 64, 0, stream>>>(w_ee, b_ee, w_eg, att_edge, c1, c0);

    // -------- CSR build (once per call) --------
    hipMemsetAsync(deg, 0, (size_t)N * sizeof(unsigned), stream);
    hist_kernel<<<edgeBlocks, blk, 0, stream>>>(ei, deg, E);
    scan1_kernel<<<nodeBlocks, blk, 0, stream>>>(deg, rp, bsum, N);
    scan2_kernel<<<1, 1024, 0, stream>>>(bsum, boff, nodeBlocks);
    scan3_kernel<<<nodeBlocks, blk, 0, stream>>>(rp, wp, boff, N, E);
    csr_scatter_kernel<<<edgeBlocks, blk, 0, stream>>>(ei, eattr, wp, col, eas, E);

    for (int l = 0; l < L; l++) {
        gat_node_kernel<<<nodeWaveBlocks, blk, 0, stream>>>(
            h, w_gat + (size_t)l * 4096, att_src + l * 64, att_dst + l * 64,
            hw, a_s, a_d, N);
        gat_fused_kernel<<<nodeWaveBlocks, blk, 0, stream>>>(
            rp, col, eas, hw, a_s, a_d, c1 + l * 4, c0 + l * 4,
            h, b_gat + l * 64, ln_g + l * 64, ln_b + l * 64, N);
    }
    out_kernel<<<nodeWaveBlocks, blk, 0, stream>>>(h, w_out, b_out, (float*)d_out, N);
}

// Round 3
// 882.687 us; speedup vs baseline: 3.0287x; 1.1584x over previous
//
#include <hip/hip_runtime.h>
#include <hip/hip_bf16.h>

#define NIN 6
#define HIDN 64
#define NHEAD 4

// ================= node encoder: wave per node. h = relu(x@w1+b1)@w2+b2 =====
__global__ __launch_bounds__(256) void encode_kernel(
    const float* __restrict__ x,
    const float* __restrict__ w1, const float* __restrict__ b1,
    const float* __restrict__ w2, const float* __restrict__ b2,
    float* __restrict__ h, int N) {
    int t = blockIdx.x * blockDim.x + threadIdx.x;
    int n = t >> 6, j = t & 63;
    if (n >= N) return;
    float acc = b1[j];
#pragma unroll
    for (int i = 0; i < NIN; i++) acc += x[n * NIN + i] * w1[i * HIDN + j];
    float hid = acc > 0.f ? acc : 0.f;
    float acc2 = b2[j];
#pragma unroll
    for (int k = 0; k < HIDN; k++) acc2 += __shfl(hid, k) * w2[k * HIDN + j];
    h[n * HIDN + j] = acc2;
}

// ====== tiny per-layer edge-attn constants: a_e[i,h] = eattr[i]*c1 + c0 =====
__global__ void consts_kernel(const float* __restrict__ w_ee, const float* __restrict__ b_ee,
                              const float* __restrict__ w_eg, const float* __restrict__ att_edge,
                              float* __restrict__ c1, float* __restrict__ c0) {
    int t = threadIdx.x;
    if (t >= 12) return;
    int l = t >> 2, hh = t & 3;
    float s1 = 0.f, s0 = 0.f;
    for (int j = 0; j < HIDN; j++) {
        float wj = 0.f;
        for (int d = 0; d < 16; d++)
            wj += w_eg[l * 4096 + j * 64 + hh * 16 + d] * att_edge[l * 64 + hh * 16 + d];
        s1 += w_ee[j] * wj;
        s0 += b_ee[j] * wj;
    }
    c1[l * 4 + hh] = s1;
    c0[l * 4 + hh] = s0;
}

// ================= CSR build: histogram -> scan -> scatter ==================
__global__ __launch_bounds__(256) void hist_kernel(const int* __restrict__ ei,
                                                   unsigned* __restrict__ deg, int E) {
    int e = blockIdx.x * 256 + threadIdx.x;
    if (e < E) atomicAdd(&deg[ei[E + e]], 1u);
}

__global__ __launch_bounds__(256) void scan1_kernel(const unsigned* __restrict__ deg,
                                                    unsigned* __restrict__ rp,
                                                    unsigned* __restrict__ bsum, int N) {
    __shared__ unsigned sm[256];
    int t = threadIdx.x, i = blockIdx.x * 256 + t;
    unsigned v = (i < N) ? deg[i] : 0u;
    sm[t] = v;
    __syncthreads();
    unsigned x = v;
    for (int o = 1; o < 256; o <<= 1) {
        unsigned add = (t >= o) ? sm[t - o] : 0u;
        __syncthreads();
        x += add; sm[t] = x;
        __syncthreads();
    }
    if (i < N) rp[i] = x - v;                 // block-local exclusive
    if (t == 255) bsum[blockIdx.x] = x;       // block total
}

__global__ void scan2_kernel(const unsigned* __restrict__ bsum,
                             unsigned* __restrict__ boff, int nb) {
    __shared__ unsigned sm[1024];
    int t = threadIdx.x;
    unsigned v = (t < nb) ? bsum[t] : 0u;
    sm[t] = v;
    __syncthreads();
    unsigned x = v;
    for (int o = 1; o < 1024; o <<= 1) {
        unsigned add = (t >= o) ? sm[t - o] : 0u;
        __syncthreads();
        x += add; sm[t] = x;
        __syncthreads();
    }
    if (t < nb) boff[t] = x - v;              // exclusive
}

__global__ __launch_bounds__(256) void scan3_kernel(unsigned* __restrict__ rp,
                                                    unsigned* __restrict__ wp,
                                                    const unsigned* __restrict__ boff,
                                                    int N, int E) {
    int i = blockIdx.x * 256 + threadIdx.x;
    if (i < N) {
        unsigned r = rp[i] + boff[blockIdx.x];
        rp[i] = r;
        wp[i] = r;
    }
    if (i == 0) rp[N] = (unsigned)E;
}

__global__ __launch_bounds__(256) void csr_scatter_kernel(
    const int* __restrict__ ei, const float* __restrict__ eattr,
    unsigned* __restrict__ wp, int* __restrict__ col, float* __restrict__ eas, int E) {
    int e = blockIdx.x * 256 + threadIdx.x;
    if (e >= E) return;
    int s = ei[e], d = ei[E + e];
    unsigned p = atomicAdd(&wp[d], 1u);
    col[p] = s;
    eas[p] = eattr[e];
}

// ========== per-layer node transform: hw = h@w_gat[l]; a_s, a_d dots ========
__global__ __launch_bounds__(256) void gat_node_kernel(
    const float* __restrict__ h, const float* __restrict__ wg,
    const float* __restrict__ att_s, const float* __restrict__ att_d,
    float* __restrict__ hw, float* __restrict__ a_s, float* __restrict__ a_d, int N) {
    int t = blockIdx.x * blockDim.x + threadIdx.x;
    int n = t >> 6, j = t & 63;
    if (n >= N) return;
    float hv = h[n * HIDN + j];
    float acc = 0.f;
#pragma unroll
    for (int k = 0; k < HIDN; k++) acc += __shfl(hv, k) * wg[k * HIDN + j];
    hw[n * HIDN + j] = acc;
    float ts = acc * att_s[j];
    float td = acc * att_d[j];
#pragma unroll
    for (int o = 8; o > 0; o >>= 1) {
        ts += __shfl_xor(ts, o);
        td += __shfl_xor(td, o);
    }
    if ((j & 15) == 0) {
        int hh = j >> 4;
        a_s[n * NHEAD + hh] = ts;
        a_d[n * NHEAD + hh] = td;
    }
}

// ===== fused per-layer edge pipeline: wave per dst node ====================
// score -> online softmax (butterfly reductions) -> weighted agg of hw[src]
// -> +b_gat, ELU, +h residual, LayerNorm -> write h. No atomics.
// Aggregation: weights stashed in LDS (ex[64][4] per wave), inner loop
// unrolled x4 with 4 independent accumulators -> 4 gathers in flight.
__global__ __launch_bounds__(256) void gat_fused_kernel(
    const unsigned* __restrict__ rp, const int* __restrict__ col,
    const float* __restrict__ eas, const float* __restrict__ hw,
    const float* __restrict__ a_s, const float* __restrict__ a_d,
    const float* __restrict__ c1, const float* __restrict__ c0,
    float* __restrict__ h, const float* __restrict__ bg,
    const float* __restrict__ g, const float* __restrict__ b, int N) {
    __shared__ float exl[4 * 256];   // per wave: 64 edges x 4 heads
    int t = blockIdx.x * blockDim.x + threadIdx.x;
    int n = t >> 6, j = t & 63;
    if (n >= N) return;
    int hh = j >> 4;
    float* myex = exl + ((threadIdx.x >> 6) << 8);

    unsigned beg = rp[n];
    int deg = (int)(rp[n + 1] - beg);

    float4 ad4 = *(const float4*)(a_d + (size_t)n * 4);
    float4 C1 = *(const float4*)c1;
    float4 C0 = *(const float4*)c0;

    float m0 = -1e30f, m1 = -1e30f, m2 = -1e30f, m3 = -1e30f;
    float s0 = 0.f, s1 = 0.f, s2 = 0.f, s3 = 0.f;
    float accA = 0.f, accB = 0.f, accC = 0.f, accD = 0.f;

    for (int cs = 0; cs < deg; cs += 64) {
        int i = cs + j;
        bool act = i < deg;
        int src = act ? col[beg + i] : 0;
        float ea = act ? eas[beg + i] : 0.f;
        float sc0 = -1e30f, sc1 = -1e30f, sc2 = -1e30f, sc3 = -1e30f;
        if (act) {
            float4 as4 = *(const float4*)(a_s + (size_t)src * 4);
            sc0 = as4.x + ad4.x + ea * C1.x + C0.x;
            sc1 = as4.y + ad4.y + ea * C1.y + C0.y;
            sc2 = as4.z + ad4.z + ea * C1.z + C0.z;
            sc3 = as4.w + ad4.w + ea * C1.w + C0.w;
            sc0 = sc0 >= 0.f ? sc0 : 0.2f * sc0;
            sc1 = sc1 >= 0.f ? sc1 : 0.2f * sc1;
            sc2 = sc2 >= 0.f ? sc2 : 0.2f * sc2;
            sc3 = sc3 >= 0.f ? sc3 : 0.2f * sc3;
        }
        // chunk max per head (butterfly -> all lanes)
        float x0 = sc0, x1 = sc1, x2 = sc2, x3 = sc3;
#pragma unroll
        for (int o = 32; o > 0; o >>= 1) {
            x0 = fmaxf(x0, __shfl_xor(x0, o));
            x1 = fmaxf(x1, __shfl_xor(x1, o));
            x2 = fmaxf(x2, __shfl_xor(x2, o));
            x3 = fmaxf(x3, __shfl_xor(x3, o));
        }
        float nm0 = fmaxf(m0, x0), nm1 = fmaxf(m1, x1);
        float nm2 = fmaxf(m2, x2), nm3 = fmaxf(m3, x3);
        float r0 = __expf(m0 - nm0), r1 = __expf(m1 - nm1);
        float r2 = __expf(m2 - nm2), r3 = __expf(m3 - nm3);
        m0 = nm0; m1 = nm1; m2 = nm2; m3 = nm3;

        float ex0 = act ? __expf(sc0 - nm0) : 0.f;
        float ex1 = act ? __expf(sc1 - nm1) : 0.f;
        float ex2 = act ? __expf(sc2 - nm2) : 0.f;
        float ex3 = act ? __expf(sc3 - nm3) : 0.f;

        // stash weights for the aggregation phase: myex[i*4 + head]
        *(float4*)(myex + (j << 2)) = make_float4(ex0, ex1, ex2, ex3);

        // chunk sum per head
        float y0 = ex0, y1 = ex1, y2 = ex2, y3 = ex3;
#pragma unroll
        for (int o = 32; o > 0; o >>= 1) {
            y0 += __shfl_xor(y0, o);
            y1 += __shfl_xor(y1, o);
            y2 += __shfl_xor(y2, o);
            y3 += __shfl_xor(y3, o);
        }
        s0 = s0 * r0 + y0; s1 = s1 * r1 + y1;
        s2 = s2 * r2 + y2; s3 = s3 * r3 + y3;

        float rj = hh == 0 ? r0 : hh == 1 ? r1 : hh == 2 ? r2 : r3;
        accA *= rj; accB *= rj; accC *= rj; accD *= rj;

        int cl = deg - cs; if (cl > 64) cl = 64;
        // padded x4 loop: lanes beyond cl hold ex=0, src=0 -> harmless
        for (int i2 = 0; i2 < cl; i2 += 4) {
            int sA = __shfl(src, i2);
            int sB = __shfl(src, i2 + 1);
            int sC = __shfl(src, i2 + 2);
            int sD = __shfl(src, i2 + 3);
            float wA = myex[((i2) << 2) + hh];
            float wB = myex[((i2 + 1) << 2) + hh];
            float wC = myex[((i2 + 2) << 2) + hh];
            float wD = myex[((i2 + 3) << 2) + hh];
            float vA = hw[(size_t)sA * HIDN + j];
            float vB = hw[(size_t)sB * HIDN + j];
            float vC = hw[(size_t)sC * HIDN + j];
            float vD = hw[(size_t)sD * HIDN + j];
            accA += wA * vA;
            accB += wB * vB;
            accC += wC * vC;
            accD += wD * vD;
        }
    }
    float den = hh == 0 ? s0 : hh == 1 ? s1 : hh == 2 ? s2 : s3;
    float agg = ((accA + accB) + (accC + accD)) / (den + 1e-16f);

    // epilogue: h = LN(h + elu(agg + bg))
    float a = agg + bg[j];
    float el = a > 0.f ? a : (__expf(a) - 1.f);
    float v = h[(size_t)n * HIDN + j] + el;
    float s = v, sq = v * v;
#pragma unroll
    for (int o = 32; o > 0; o >>= 1) {
        s += __shfl_xor(s, o);
        sq += __shfl_xor(sq, o);
    }
    float mean = s * (1.f / 64.f);
    float var = sq * (1.f / 64.f) - mean * mean;
    float r = rsqrtf(var + 1e-5f);
    h[(size_t)n * HIDN + j] = (v - mean) * r * g[j] + b[j];
}

// ================= final projection: out = h @ w_out + b_out ===============
__global__ __launch_bounds__(256) void out_kernel(
    const float* __restrict__ h, const float* __restrict__ w,
    const float* __restrict__ b, float* __restrict__ out, int N) {
    int t = blockIdx.x * blockDim.x + threadIdx.x;
    int n = t >> 6, j = t & 63;
    if (n >= N) return;
    float hv = h[(size_t)n * HIDN + j];
    float acc = b[j];
#pragma unroll
    for (int k = 0; k < HIDN; k++) acc += __shfl(hv, k) * w[k * HIDN + j];
    out[(size_t)n * HIDN + j] = acc;
}

extern "C" void kernel_launch(void* const* d_in, const int* in_sizes, int n_in,
                              void* d_out, int out_size, void* d_ws, size_t ws_size,
                              hipStream_t stream) {
    const float* x      = (const float*)d_in[0];
    const int*   ei     = (const int*)d_in[1];
    const float* eattr  = (const float*)d_in[2];
    const float* w_ne1  = (const float*)d_in[3];
    const float* b_ne1  = (const float*)d_in[4];
    const float* w_ne2  = (const float*)d_in[5];
    const float* b_ne2  = (const float*)d_in[6];
    const float* w_ee   = (const float*)d_in[7];
    const float* b_ee   = (const float*)d_in[8];
    const float* w_gat  = (const float*)d_in[9];
    const float* w_eg   = (const float*)d_in[10];
    const float* att_src= (const float*)d_in[11];
    const float* att_dst= (const float*)d_in[12];
    const float* att_edge=(const float*)d_in[13];
    const float* b_gat  = (const float*)d_in[14];
    const float* ln_g   = (const float*)d_in[15];
    const float* ln_b   = (const float*)d_in[16];
    const float* w_out  = (const float*)d_in[17];
    const float* b_out  = (const float*)d_in[18];

    const int N = in_sizes[0] / NIN;
    const int E = in_sizes[2];
    const int L = 3;

    // -------- workspace layout --------
    float* ws   = (float*)d_ws;
    float* h    = ws;                          // N*64
    float* hw   = h + (size_t)N * 64;          // N*64
    float* a_s  = hw + (size_t)N * 64;         // N*4
    float* a_d  = a_s + (size_t)N * 4;         // N*4
    float* c1   = a_d + (size_t)N * 4;         // 12
    float* c0   = c1 + 12;                     // 12
    float* eas  = c0 + 12;                     // E (dst-sorted edge_attr)
    int*   col  = (int*)(eas + (size_t)E);     // E (dst-sorted src)
    unsigned* deg = (unsigned*)(col + (size_t)E);   // N
    unsigned* rp  = deg + (size_t)N;                // N+1
    unsigned* wp  = rp + (size_t)N + 1;             // N
    unsigned* bsum= wp + (size_t)N;                 // <=1024
    unsigned* boff= bsum + 1024;                    // <=1024

    dim3 blk(256);
    int nodeWaveBlocks = (int)(((size_t)N * 64 + 255) / 256);
    int edgeBlocks = (E + 255) / 256;
    int nodeBlocks = (N + 255) / 256;   // scan grid, one elem per thread

    encode_kernel<<<nodeWaveBlocks, blk, 0, stream>>>(x, w_ne1, b_ne1, w_ne2, b_ne2, h, N);
    consts_kernel<<<1, 64, 0, stream>>>(w_ee, b_ee, w_eg, att_edge, c1, c0);

    // -------- CSR build (once per call) --------
    hipMemsetAsync(deg, 0, (size_t)N * sizeof(unsigned), stream);
    hist_kernel<<<edgeBlocks, blk, 0, stream>>>(ei, deg, E);
    scan1_kernel<<<nodeBlocks, blk, 0, stream>>>(deg, rp, bsum, N);
    scan2_kernel<<<1, 1024, 0, stream>>>(bsum, boff, nodeBlocks);
    scan3_kernel<<<nodeBlocks, blk, 0, stream>>>(rp, wp, boff, N, E);
    csr_scatter_kernel<<<edgeBlocks, blk, 0, stream>>>(ei, eattr, wp, col, eas, E);

    for (int l = 0; l < L; l++) {
        gat_node_kernel<<<nodeWaveBlocks, blk, 0, stream>>>(
            h, w_gat + (size_t)l * 4096, att_src + l * 64, att_dst + l * 64,
            hw, a_s, a_d, N);
        gat_fused_kernel<<<nodeWaveBlocks, blk, 0, stream>>>(
            rp, col, eas, hw, a_s, a_d, c1 + l * 4, c0 + l * 4,
            h, b_gat + l * 64, ln_g + l * 64, ln_b + l * 64, N);
    }
    out_kernel<<<nodeWaveBlocks, blk, 0, stream>>>(h, w_out, b_out, (float*)d_out, N);
}

// Round 4
// 764.186 us; speedup vs baseline: 3.4984x; 1.1551x over previous
//
#include <hip/hip_runtime.h>
#include <hip/hip_bf16.h>

#define NIN 6
#define HIDN 64
#define NHEAD 4

// ---- wave-local transform epilogue: from h-row (hv, one elem per lane)
// compute hw = h@wg, head-dots a_s/a_d, for the NEXT layer's edge pass.
__device__ __forceinline__ void transform_row(
    float hv, int n, int j, const float* __restrict__ wg,
    const float* __restrict__ att_s, const float* __restrict__ att_d,
    float* __restrict__ hw, float* __restrict__ a_s, float* __restrict__ a_d) {
    float acc = 0.f;
#pragma unroll
    for (int k = 0; k < HIDN; k++) acc += __shfl(hv, k) * wg[k * HIDN + j];
    hw[(size_t)n * HIDN + j] = acc;
    float ts = acc * att_s[j];
    float td = acc * att_d[j];
#pragma unroll
    for (int o = 8; o > 0; o >>= 1) {
        ts += __shfl_xor(ts, o);
        td += __shfl_xor(td, o);
    }
    if ((j & 15) == 0) {
        a_s[n * NHEAD + (j >> 4)] = ts;
        a_d[n * NHEAD + (j >> 4)] = td;
    }
}

// ========== node encoder + layer-0 transform, wave per node ================
__global__ __launch_bounds__(256) void encode_t_kernel(
    const float* __restrict__ x,
    const float* __restrict__ w1, const float* __restrict__ b1,
    const float* __restrict__ w2, const float* __restrict__ b2,
    const float* __restrict__ wg0, const float* __restrict__ atts0,
    const float* __restrict__ attd0,
    float* __restrict__ h, float* __restrict__ hw,
    float* __restrict__ a_s, float* __restrict__ a_d, int N) {
    int t = blockIdx.x * blockDim.x + threadIdx.x;
    int n = t >> 6, j = t & 63;
    if (n >= N) return;
    float acc = b1[j];
#pragma unroll
    for (int i = 0; i < NIN; i++) acc += x[n * NIN + i] * w1[i * HIDN + j];
    float hid = acc > 0.f ? acc : 0.f;
    float acc2 = b2[j];
#pragma unroll
    for (int k = 0; k < HIDN; k++) acc2 += __shfl(hid, k) * w2[k * HIDN + j];
    h[(size_t)n * HIDN + j] = acc2;
    transform_row(acc2, n, j, wg0, atts0, attd0, hw, a_s, a_d);
}

// ====== tiny per-layer edge-attn constants: a_e[i,h] = eattr[i]*c1 + c0 =====
__global__ void consts_kernel(const float* __restrict__ w_ee, const float* __restrict__ b_ee,
                              const float* __restrict__ w_eg, const float* __restrict__ att_edge,
                              float* __restrict__ c1, float* __restrict__ c0) {
    int t = threadIdx.x;
    if (t >= 12) return;
    int l = t >> 2, hh = t & 3;
    float s1 = 0.f, s0 = 0.f;
    for (int j = 0; j < HIDN; j++) {
        float wj = 0.f;
        for (int d = 0; d < 16; d++)
            wj += w_eg[l * 4096 + j * 64 + hh * 16 + d] * att_edge[l * 64 + hh * 16 + d];
        s1 += w_ee[j] * wj;
        s0 += b_ee[j] * wj;
    }
    c1[l * 4 + hh] = s1;
    c0[l * 4 + hh] = s0;
}

// ================= CSR build: histogram -> scan -> scatter ==================
__global__ __launch_bounds__(256) void hist_kernel(const int* __restrict__ ei,
                                                   unsigned* __restrict__ deg, int E) {
    int e = blockIdx.x * 256 + threadIdx.x;
    if (e < E) atomicAdd(&deg[ei[E + e]], 1u);
}

__global__ __launch_bounds__(256) void scan1_kernel(const unsigned* __restrict__ deg,
                                                    unsigned* __restrict__ rp,
                                                    unsigned* __restrict__ bsum, int N) {
    __shared__ unsigned sm[256];
    int t = threadIdx.x, i = blockIdx.x * 256 + t;
    unsigned v = (i < N) ? deg[i] : 0u;
    sm[t] = v;
    __syncthreads();
    unsigned x = v;
    for (int o = 1; o < 256; o <<= 1) {
        unsigned add = (t >= o) ? sm[t - o] : 0u;
        __syncthreads();
        x += add; sm[t] = x;
        __syncthreads();
    }
    if (i < N) rp[i] = x - v;
    if (t == 255) bsum[blockIdx.x] = x;
}

__global__ void scan2_kernel(const unsigned* __restrict__ bsum,
                             unsigned* __restrict__ boff, int nb) {
    __shared__ unsigned sm[1024];
    int t = threadIdx.x;
    unsigned v = (t < nb) ? bsum[t] : 0u;
    sm[t] = v;
    __syncthreads();
    unsigned x = v;
    for (int o = 1; o < 1024; o <<= 1) {
        unsigned add = (t >= o) ? sm[t - o] : 0u;
        __syncthreads();
        x += add; sm[t] = x;
        __syncthreads();
    }
    if (t < nb) boff[t] = x - v;
}

__global__ __launch_bounds__(256) void scan3_kernel(unsigned* __restrict__ rp,
                                                    unsigned* __restrict__ wp,
                                                    const unsigned* __restrict__ boff,
                                                    int N, int E) {
    int i = blockIdx.x * 256 + threadIdx.x;
    if (i < N) {
        unsigned r = rp[i] + boff[blockIdx.x];
        rp[i] = r;
        wp[i] = r;
    }
    if (i == 0) rp[N] = (unsigned)E;
}

__global__ __launch_bounds__(256) void csr_scatter_kernel(
    const int* __restrict__ ei, const float* __restrict__ eattr,
    unsigned* __restrict__ wp, int* __restrict__ col, float* __restrict__ eas, int E) {
    int e = blockIdx.x * 256 + threadIdx.x;
    if (e >= E) return;
    int s = ei[e], d = ei[E + e];
    unsigned p = atomicAdd(&wp[d], 1u);
    col[p] = s;
    eas[p] = eattr[e];
}

// ===== fused per-layer edge pipeline: wave per dst node ====================
// score -> transposed-LDS online softmax -> x4-unrolled weighted agg of
// hw[src] -> bias/ELU/residual/LayerNorm -> (LAST ? out-proj : h-write +
// next-layer transform). No atomics, no inter-wave sync.
template <bool LAST>
__global__ __launch_bounds__(256) void gat_fused_kernel(
    const unsigned* __restrict__ rp, const int* __restrict__ col,
    const float* __restrict__ eas, const float* __restrict__ hw,
    const float* __restrict__ a_s, const float* __restrict__ a_d,
    const float* __restrict__ c1, const float* __restrict__ c0,
    float* __restrict__ h, const float* __restrict__ bg,
    const float* __restrict__ g, const float* __restrict__ b,
    const float* __restrict__ wg_n, const float* __restrict__ atts_n,
    const float* __restrict__ attd_n,
    float* __restrict__ hw_n, float* __restrict__ as_n, float* __restrict__ ad_n,
    const float* __restrict__ w_out, const float* __restrict__ b_out,
    float* __restrict__ out, int N) {
    __shared__ float exl[4 * 256];   // per wave: 64 edges x 4 heads (scores->weights)
    int t = blockIdx.x * blockDim.x + threadIdx.x;
    int n = t >> 6, j = t & 63;
    if (n >= N) return;
    int hh = j >> 4;          // this lane's owned head
    int l16 = j & 15;         // edge sub-index within head group
    float* myex = exl + ((threadIdx.x >> 6) << 8);

    unsigned beg = rp[n];
    int deg = (int)(rp[n + 1] - beg);

    float4 ad4 = *(const float4*)(a_d + (size_t)n * 4);
    float4 C1 = *(const float4*)c1;
    float4 C0 = *(const float4*)c0;

    float m = -1e30f, ssum = 0.f;   // own-head online softmax state
    float accA = 0.f, accB = 0.f, accC = 0.f, accD = 0.f;

    for (int cs = 0; cs < deg; cs += 64) {
        int i = cs + j;
        bool act = i < deg;
        int src = act ? col[beg + i] : 0;
        float ea = act ? eas[beg + i] : 0.f;
        float sc0 = -1e30f, sc1 = -1e30f, sc2 = -1e30f, sc3 = -1e30f;
        if (act) {
            float4 as4 = *(const float4*)(a_s + (size_t)src * 4);
            sc0 = as4.x + ad4.x + ea * C1.x + C0.x;
            sc1 = as4.y + ad4.y + ea * C1.y + C0.y;
            sc2 = as4.z + ad4.z + ea * C1.z + C0.z;
            sc3 = as4.w + ad4.w + ea * C1.w + C0.w;
            sc0 = sc0 >= 0.f ? sc0 : 0.2f * sc0;
            sc1 = sc1 >= 0.f ? sc1 : 0.2f * sc1;
            sc2 = sc2 >= 0.f ? sc2 : 0.2f * sc2;
            sc3 = sc3 >= 0.f ? sc3 : 0.2f * sc3;
        }
        // stash raw scores: word (edge*4 + head)
        *(float4*)(myex + (j << 2)) = make_float4(sc0, sc1, sc2, sc3);

        int cl = deg - cs; if (cl > 64) cl = 64;
        // transposed read: this lane's head, edges l16 + {0,16,32,48}
        float s0 = myex[((l16     ) << 2) + hh];
        float s1 = myex[((l16 + 16) << 2) + hh];
        float s2 = myex[((l16 + 32) << 2) + hh];
        float s3 = myex[((l16 + 48) << 2) + hh];
        float cmax = fmaxf(fmaxf(s0, s1), fmaxf(s2, s3));
#pragma unroll
        for (int o = 8; o > 0; o >>= 1) cmax = fmaxf(cmax, __shfl_xor(cmax, o));
        float nm = fmaxf(m, cmax);
        float r = __expf(m - nm);
        m = nm;
        float e0 = (l16      < cl) ? __expf(s0 - nm) : 0.f;
        float e1 = (l16 + 16 < cl) ? __expf(s1 - nm) : 0.f;
        float e2 = (l16 + 32 < cl) ? __expf(s2 - nm) : 0.f;
        float e3 = (l16 + 48 < cl) ? __expf(s3 - nm) : 0.f;
        // write weights back to the same words this lane read
        myex[((l16     ) << 2) + hh] = e0;
        myex[((l16 + 16) << 2) + hh] = e1;
        myex[((l16 + 32) << 2) + hh] = e2;
        myex[((l16 + 48) << 2) + hh] = e3;
        float csum = (e0 + e1) + (e2 + e3);
#pragma unroll
        for (int o = 8; o > 0; o >>= 1) csum += __shfl_xor(csum, o);
        ssum = ssum * r + csum;
        accA *= r; accB *= r; accC *= r; accD *= r;

        // x4-unrolled aggregation: 4 gathers in flight
        for (int i2 = 0; i2 < cl; i2 += 4) {
            int sA = __shfl(src, i2);
            int sB = __shfl(src, i2 + 1);
            int sC = __shfl(src, i2 + 2);
            int sD = __shfl(src, i2 + 3);
            float wA = myex[((i2    ) << 2) + hh];
            float wB = myex[((i2 + 1) << 2) + hh];
            float wC = myex[((i2 + 2) << 2) + hh];
            float wD = myex[((i2 + 3) << 2) + hh];
            float vA = hw[(size_t)sA * HIDN + j];
            float vB = hw[(size_t)sB * HIDN + j];
            float vC = hw[(size_t)sC * HIDN + j];
            float vD = hw[(size_t)sD * HIDN + j];
            accA += wA * vA;
            accB += wB * vB;
            accC += wC * vC;
            accD += wD * vD;
        }
    }
    float agg = ((accA + accB) + (accC + accD)) / (ssum + 1e-16f);

    // epilogue: hv = LN(h + elu(agg + bg))
    float a = agg + bg[j];
    float el = a > 0.f ? a : (__expf(a) - 1.f);
    float v = h[(size_t)n * HIDN + j] + el;
    float s = v, sq = v * v;
#pragma unroll
    for (int o = 32; o > 0; o >>= 1) {
        s += __shfl_xor(s, o);
        sq += __shfl_xor(sq, o);
    }
    float mean = s * (1.f / 64.f);
    float var = sq * (1.f / 64.f) - mean * mean;
    float rr = rsqrtf(var + 1e-5f);
    float hv = (v - mean) * rr * g[j] + b[j];

    if (LAST) {
        // out = hv-row @ w_out + b_out
        float acc = b_out[j];
#pragma unroll
        for (int k = 0; k < HIDN; k++) acc += __shfl(hv, k) * w_out[k * HIDN + j];
        out[(size_t)n * HIDN + j] = acc;
    } else {
        h[(size_t)n * HIDN + j] = hv;
        transform_row(hv, n, j, wg_n, atts_n, attd_n, hw_n, as_n, ad_n);
    }
}

extern "C" void kernel_launch(void* const* d_in, const int* in_sizes, int n_in,
                              void* d_out, int out_size, void* d_ws, size_t ws_size,
                              hipStream_t stream) {
    const float* x      = (const float*)d_in[0];
    const int*   ei     = (const int*)d_in[1];
    const float* eattr  = (const float*)d_in[2];
    const float* w_ne1  = (const float*)d_in[3];
    const float* b_ne1  = (const float*)d_in[4];
    const float* w_ne2  = (const float*)d_in[5];
    const float* b_ne2  = (const float*)d_in[6];
    const float* w_ee   = (const float*)d_in[7];
    const float* b_ee   = (const float*)d_in[8];
    const float* w_gat  = (const float*)d_in[9];
    const float* w_eg   = (const float*)d_in[10];
    const float* att_src= (const float*)d_in[11];
    const float* att_dst= (const float*)d_in[12];
    const float* att_edge=(const float*)d_in[13];
    const float* b_gat  = (const float*)d_in[14];
    const float* ln_g   = (const float*)d_in[15];
    const float* ln_b   = (const float*)d_in[16];
    const float* w_out  = (const float*)d_in[17];
    const float* b_out  = (const float*)d_in[18];

    const int N = in_sizes[0] / NIN;
    const int E = in_sizes[2];

    // -------- workspace layout (double-buffered hw / a_s / a_d) --------
    float* ws   = (float*)d_ws;
    float* h    = ws;                           // N*64
    float* hwA  = h + (size_t)N * 64;           // N*64
    float* hwB  = hwA + (size_t)N * 64;         // N*64
    float* asA  = hwB + (size_t)N * 64;         // N*4
    float* asB  = asA + (size_t)N * 4;          // N*4
    float* adA  = asB + (size_t)N * 4;          // N*4
    float* adB  = adA + (size_t)N * 4;          // N*4
    float* c1   = adB + (size_t)N * 4;          // 12
    float* c0   = c1 + 12;                      // 12
    float* eas  = c0 + 12;                      // E
    int*   col  = (int*)(eas + (size_t)E);      // E
    unsigned* deg = (unsigned*)(col + (size_t)E);   // N
    unsigned* rp  = deg + (size_t)N;                // N+1
    unsigned* wp  = rp + (size_t)N + 1;             // N
    unsigned* bsum= wp + (size_t)N;                 // <=1024
    unsigned* boff= bsum + 1024;                    // <=1024

    dim3 blk(256);
    int nodeWaveBlocks = (int)(((size_t)N * 64 + 255) / 256);
    int edgeBlocks = (E + 255) / 256;
    int nodeBlocks = (N + 255) / 256;

    // -------- CSR build --------
    hipMemsetAsync(deg, 0, (size_t)N * sizeof(unsigned), stream);
    hist_kernel<<<edgeBlocks, blk, 0, stream>>>(ei, deg, E);
    scan1_kernel<<<nodeBlocks, blk, 0, stream>>>(deg, rp, bsum, N);
    scan2_kernel<<<1, 1024, 0, stream>>>(bsum, boff, nodeBlocks);
    scan3_kernel<<<nodeBlocks, blk, 0, stream>>>(rp, wp, boff, N, E);
    csr_scatter_kernel<<<edgeBlocks, blk, 0, stream>>>(ei, eattr, wp, col, eas, E);

    consts_kernel<<<1, 64, 0, stream>>>(w_ee, b_ee, w_eg, att_edge, c1, c0);
    encode_t_kernel<<<nodeWaveBlocks, blk, 0, stream>>>(
        x, w_ne1, b_ne1, w_ne2, b_ne2,
        w_gat, att_src, att_dst, h, hwA, asA, adA, N);

    // layer 0: read A, produce layer-1 transform into B
    gat_fused_kernel<false><<<nodeWaveBlocks, blk, 0, stream>>>(
        rp, col, eas, hwA, asA, adA, c1 + 0, c0 + 0,
        h, b_gat + 0, ln_g + 0, ln_b + 0,
        w_gat + 4096, att_src + 64, att_dst + 64, hwB, asB, adB,
        nullptr, nullptr, nullptr, N);
    // layer 1: read B, produce layer-2 transform into A
    gat_fused_kernel<false><<<nodeWaveBlocks, blk, 0, stream>>>(
        rp, col, eas, hwB, asB, adB, c1 + 4, c0 + 4,
        h, b_gat + 64, ln_g + 64, ln_b + 64,
        w_gat + 2 * 4096, att_src + 128, att_dst + 128, hwA, asA, adA,
        nullptr, nullptr, nullptr, N);
    // layer 2: read A, out-projection epilogue
    gat_fused_kernel<true><<<nodeWaveBlocks, blk, 0, stream>>>(
        rp, col, eas, hwA, asA, adA, c1 + 8, c0 + 8,
        h, b_gat + 128, ln_g + 128, ln_b + 128,
        nullptr, nullptr, nullptr, nullptr, nullptr, nullptr,
        w_out, b_out, (float*)d_out, N);
}

// Round 5
// 635.627 us; speedup vs baseline: 4.2060x; 1.2023x over previous
//
#include <hip/hip_runtime.h>
#include <hip/hip_bf16.h>

#define NIN 6
#define HIDN 64
#define NHEAD 4

// ========== encoder stage 1: hid = relu(x@w1 + b1), wave per node ==========
__global__ __launch_bounds__(256) void encode1_kernel(
    const float* __restrict__ x,
    const float* __restrict__ w1, const float* __restrict__ b1,
    float* __restrict__ hid, int N) {
    int t = blockIdx.x * blockDim.x + threadIdx.x;
    int n = t >> 6, j = t & 63;
    if (n >= N) return;
    float acc = b1[j];
#pragma unroll
    for (int i = 0; i < NIN; i++) acc += x[n * NIN + i] * w1[i * HIDN + j];
    hid[(size_t)n * HIDN + j] = acc > 0.f ? acc : 0.f;
}

// ========== generic 64x64 fp32 matmul: weight-stationary, scalar h-row =====
// dst[n][j] = sum_k src[n][k] * W[k][j] (+ bias[j]).
// Each lane holds W column j in VGPRs; node index is wave-uniform so the
// src-row float4 loads become s_load + v_fmac (1 inst/MAC).
// ATTN: also emit a_s/a_d head dots for the GAT edge pass.
template <bool ATTN, bool BIAS>
__global__ __launch_bounds__(256) void mm64_kernel(
    const float* __restrict__ src, const float* __restrict__ W,
    const float* __restrict__ bias,
    const float* __restrict__ att_s, const float* __restrict__ att_d,
    float* __restrict__ dst, float* __restrict__ a_s, float* __restrict__ a_d,
    int N) {
    int j = threadIdx.x & 63;
    int wv = (blockIdx.x * blockDim.x + threadIdx.x) >> 6;
    int nw = (gridDim.x * blockDim.x) >> 6;

    float Wc[HIDN];
#pragma unroll
    for (int k = 0; k < HIDN; k++) Wc[k] = W[k * HIDN + j];
    float bj = BIAS ? bias[j] : 0.f;
    float asj = ATTN ? att_s[j] : 0.f;
    float adj = ATTN ? att_d[j] : 0.f;

    for (int n0 = wv; n0 < N; n0 += nw) {
        int n = __builtin_amdgcn_readfirstlane(n0);
        const float4* __restrict__ row = (const float4*)(src + (size_t)n * HIDN);
        float a0 = 0.f, a1 = 0.f, a2 = 0.f, a3 = 0.f;
#pragma unroll
        for (int kk = 0; kk < 16; kk++) {
            float4 r = row[kk];
            a0 += r.x * Wc[4 * kk];
            a1 += r.y * Wc[4 * kk + 1];
            a2 += r.z * Wc[4 * kk + 2];
            a3 += r.w * Wc[4 * kk + 3];
        }
        float acc = ((a0 + a1) + (a2 + a3)) + bj;
        dst[(size_t)n * HIDN + j] = acc;
        if (ATTN) {
            float ts = acc * asj;
            float td = acc * adj;
#pragma unroll
            for (int o = 8; o > 0; o >>= 1) {
                ts += __shfl_xor(ts, o);
                td += __shfl_xor(td, o);
            }
            if ((j & 15) == 0) {
                a_s[(size_t)n * NHEAD + (j >> 4)] = ts;
                a_d[(size_t)n * NHEAD + (j >> 4)] = td;
            }
        }
    }
}

// ====== tiny per-layer edge-attn constants: a_e[i,h] = eattr[i]*c1 + c0 =====
__global__ void consts_kernel(const float* __restrict__ w_ee, const float* __restrict__ b_ee,
                              const float* __restrict__ w_eg, const float* __restrict__ att_edge,
                              float* __restrict__ c1, float* __restrict__ c0) {
    int t = threadIdx.x;
    if (t >= 12) return;
    int l = t >> 2, hh = t & 3;
    float s1 = 0.f, s0 = 0.f;
    for (int j = 0; j < HIDN; j++) {
        float wj = 0.f;
        for (int d = 0; d < 16; d++)
            wj += w_eg[l * 4096 + j * 64 + hh * 16 + d] * att_edge[l * 64 + hh * 16 + d];
        s1 += w_ee[j] * wj;
        s0 += b_ee[j] * wj;
    }
    c1[l * 4 + hh] = s1;
    c0[l * 4 + hh] = s0;
}

// ================= CSR build: histogram -> scan -> scatter ==================
__global__ __launch_bounds__(256) void hist_kernel(const int* __restrict__ ei,
                                                   unsigned* __restrict__ deg, int E) {
    int e = blockIdx.x * 256 + threadIdx.x;
    if (e < E) atomicAdd(&deg[ei[E + e]], 1u);
}

__global__ __launch_bounds__(256) void scan1_kernel(const unsigned* __restrict__ deg,
                                                    unsigned* __restrict__ rp,
                                                    unsigned* __restrict__ bsum, int N) {
    __shared__ unsigned sm[256];
    int t = threadIdx.x, i = blockIdx.x * 256 + t;
    unsigned v = (i < N) ? deg[i] : 0u;
    sm[t] = v;
    __syncthreads();
    unsigned x = v;
    for (int o = 1; o < 256; o <<= 1) {
        unsigned add = (t >= o) ? sm[t - o] : 0u;
        __syncthreads();
        x += add; sm[t] = x;
        __syncthreads();
    }
    if (i < N) rp[i] = x - v;
    if (t == 255) bsum[blockIdx.x] = x;
}

__global__ void scan2_kernel(const unsigned* __restrict__ bsum,
                             unsigned* __restrict__ boff, int nb) {
    __shared__ unsigned sm[1024];
    int t = threadIdx.x;
    unsigned v = (t < nb) ? bsum[t] : 0u;
    sm[t] = v;
    __syncthreads();
    unsigned x = v;
    for (int o = 1; o < 1024; o <<= 1) {
        unsigned add = (t >= o) ? sm[t - o] : 0u;
        __syncthreads();
        x += add; sm[t] = x;
        __syncthreads();
    }
    if (t < nb) boff[t] = x - v;
}

__global__ __launch_bounds__(256) void scan3_kernel(unsigned* __restrict__ rp,
                                                    unsigned* __restrict__ wp,
                                                    const unsigned* __restrict__ boff,
                                                    int N, int E) {
    int i = blockIdx.x * 256 + threadIdx.x;
    if (i < N) {
        unsigned r = rp[i] + boff[blockIdx.x];
        rp[i] = r;
        wp[i] = r;
    }
    if (i == 0) rp[N] = (unsigned)E;
}

__global__ __launch_bounds__(256) void csr_scatter_kernel(
    const int* __restrict__ ei, const float* __restrict__ eattr,
    unsigned* __restrict__ wp, int* __restrict__ col, float* __restrict__ eas, int E) {
    int e = blockIdx.x * 256 + threadIdx.x;
    if (e >= E) return;
    int s = ei[e], d = ei[E + e];
    unsigned p = atomicAdd(&wp[d], 1u);
    col[p] = s;
    eas[p] = eattr[e];
}

// ===== fused per-layer edge pipeline: wave per dst node ====================
// score -> transposed-LDS online softmax -> x4-unrolled weighted agg of
// hw[src] -> bias/ELU/residual/LayerNorm -> write h. No atomics.
__global__ __launch_bounds__(256) void gat_fused_kernel(
    const unsigned* __restrict__ rp, const int* __restrict__ col,
    const float* __restrict__ eas, const float* __restrict__ hw,
    const float* __restrict__ a_s, const float* __restrict__ a_d,
    const float* __restrict__ c1, const float* __restrict__ c0,
    float* __restrict__ h, const float* __restrict__ bg,
    const float* __restrict__ g, const float* __restrict__ b, int N) {
    __shared__ float exl[4 * 256];   // per wave: 64 edges x 4 heads
    int t = blockIdx.x * blockDim.x + threadIdx.x;
    int n = t >> 6, j = t & 63;
    if (n >= N) return;
    int hh = j >> 4;
    int l16 = j & 15;
    float* myex = exl + ((threadIdx.x >> 6) << 8);

    unsigned beg = rp[n];
    int deg = (int)(rp[n + 1] - beg);

    float4 ad4 = *(const float4*)(a_d + (size_t)n * 4);
    float4 C1 = *(const float4*)c1;
    float4 C0 = *(const float4*)c0;

    float m = -1e30f, ssum = 0.f;
    float accA = 0.f, accB = 0.f, accC = 0.f, accD = 0.f;

    for (int cs = 0; cs < deg; cs += 64) {
        int i = cs + j;
        bool act = i < deg;
        int src = act ? col[beg + i] : 0;
        float ea = act ? eas[beg + i] : 0.f;
        float sc0 = -1e30f, sc1 = -1e30f, sc2 = -1e30f, sc3 = -1e30f;
        if (act) {
            float4 as4 = *(const float4*)(a_s + (size_t)src * 4);
            sc0 = as4.x + ad4.x + ea * C1.x + C0.x;
            sc1 = as4.y + ad4.y + ea * C1.y + C0.y;
            sc2 = as4.z + ad4.z + ea * C1.z + C0.z;
            sc3 = as4.w + ad4.w + ea * C1.w + C0.w;
            sc0 = sc0 >= 0.f ? sc0 : 0.2f * sc0;
            sc1 = sc1 >= 0.f ? sc1 : 0.2f * sc1;
            sc2 = sc2 >= 0.f ? sc2 : 0.2f * sc2;
            sc3 = sc3 >= 0.f ? sc3 : 0.2f * sc3;
        }
        *(float4*)(myex + (j << 2)) = make_float4(sc0, sc1, sc2, sc3);

        int cl = deg - cs; if (cl > 64) cl = 64;
        float s0 = myex[((l16     ) << 2) + hh];
        float s1 = myex[((l16 + 16) << 2) + hh];
        float s2 = myex[((l16 + 32) << 2) + hh];
        float s3 = myex[((l16 + 48) << 2) + hh];
        float cmax = fmaxf(fmaxf(s0, s1), fmaxf(s2, s3));
#pragma unroll
        for (int o = 8; o > 0; o >>= 1) cmax = fmaxf(cmax, __shfl_xor(cmax, o));
        float nm = fmaxf(m, cmax);
        float r = __expf(m - nm);
        m = nm;
        float e0 = (l16      < cl) ? __expf(s0 - nm) : 0.f;
        float e1 = (l16 + 16 < cl) ? __expf(s1 - nm) : 0.f;
        float e2 = (l16 + 32 < cl) ? __expf(s2 - nm) : 0.f;
        float e3 = (l16 + 48 < cl) ? __expf(s3 - nm) : 0.f;
        myex[((l16     ) << 2) + hh] = e0;
        myex[((l16 + 16) << 2) + hh] = e1;
        myex[((l16 + 32) << 2) + hh] = e2;
        myex[((l16 + 48) << 2) + hh] = e3;
        float csum = (e0 + e1) + (e2 + e3);
#pragma unroll
        for (int o = 8; o > 0; o >>= 1) csum += __shfl_xor(csum, o);
        ssum = ssum * r + csum;
        accA *= r; accB *= r; accC *= r; accD *= r;

        for (int i2 = 0; i2 < cl; i2 += 4) {
            int sA = __shfl(src, i2);
            int sB = __shfl(src, i2 + 1);
            int sC = __shfl(src, i2 + 2);
            int sD = __shfl(src, i2 + 3);
            float wA = myex[((i2    ) << 2) + hh];
            float wB = myex[((i2 + 1) << 2) + hh];
            float wC = myex[((i2 + 2) << 2) + hh];
            float wD = myex[((i2 + 3) << 2) + hh];
            float vA = hw[(size_t)sA * HIDN + j];
            float vB = hw[(size_t)sB * HIDN + j];
            float vC = hw[(size_t)sC * HIDN + j];
            float vD = hw[(size_t)sD * HIDN + j];
            accA += wA * vA;
            accB += wB * vB;
            accC += wC * vC;
            accD += wD * vD;
        }
    }
    float agg = ((accA + accB) + (accC + accD)) / (ssum + 1e-16f);

    // epilogue: h = LN(h + elu(agg + bg))
    float a = agg + bg[j];
    float el = a > 0.f ? a : (__expf(a) - 1.f);
    float v = h[(size_t)n * HIDN + j] + el;
    float s = v, sq = v * v;
#pragma unroll
    for (int o = 32; o > 0; o >>= 1) {
        s += __shfl_xor(s, o);
        sq += __shfl_xor(sq, o);
    }
    float mean = s * (1.f / 64.f);
    float var = sq * (1.f / 64.f) - mean * mean;
    float rr = rsqrtf(var + 1e-5f);
    h[(size_t)n * HIDN + j] = (v - mean) * rr * g[j] + b[j];
}

extern "C" void kernel_launch(void* const* d_in, const int* in_sizes, int n_in,
                              void* d_out, int out_size, void* d_ws, size_t ws_size,
                              hipStream_t stream) {
    const float* x      = (const float*)d_in[0];
    const int*   ei     = (const int*)d_in[1];
    const float* eattr  = (const float*)d_in[2];
    const float* w_ne1  = (const float*)d_in[3];
    const float* b_ne1  = (const float*)d_in[4];
    const float* w_ne2  = (const float*)d_in[5];
    const float* b_ne2  = (const float*)d_in[6];
    const float* w_ee   = (const float*)d_in[7];
    const float* b_ee   = (const float*)d_in[8];
    const float* w_gat  = (const float*)d_in[9];
    const float* w_eg   = (const float*)d_in[10];
    const float* att_src= (const float*)d_in[11];
    const float* att_dst= (const float*)d_in[12];
    const float* att_edge=(const float*)d_in[13];
    const float* b_gat  = (const float*)d_in[14];
    const float* ln_g   = (const float*)d_in[15];
    const float* ln_b   = (const float*)d_in[16];
    const float* w_out  = (const float*)d_in[17];
    const float* b_out  = (const float*)d_in[18];

    const int N = in_sizes[0] / NIN;
    const int E = in_sizes[2];

    // -------- workspace layout --------
    float* ws   = (float*)d_ws;
    float* h    = ws;                           // N*64
    float* hw   = h + (size_t)N * 64;           // N*64 (also reused as hid)
    float* a_s  = hw + (size_t)N * 64;          // N*4
    float* a_d  = a_s + (size_t)N * 4;          // N*4
    float* c1   = a_d + (size_t)N * 4;          // 12
    float* c0   = c1 + 12;                      // 12
    float* eas  = c0 + 12;                      // E
    int*   col  = (int*)(eas + (size_t)E);      // E
    unsigned* deg = (unsigned*)(col + (size_t)E);   // N
    unsigned* rp  = deg + (size_t)N;                // N+1
    unsigned* wp  = rp + (size_t)N + 1;             // N
    unsigned* bsum= wp + (size_t)N;                 // <=1024
    unsigned* boff= bsum + 1024;                    // <=1024

    dim3 blk(256);
    int nodeWaveBlocks = (int)(((size_t)N * 64 + 255) / 256);
    int edgeBlocks = (E + 255) / 256;
    int nodeBlocks = (N + 255) / 256;
    int mmBlocks = 2048;    // 8192 waves, grid-stride over nodes

    // -------- CSR build --------
    hipMemsetAsync(deg, 0, (size_t)N * sizeof(unsigned), stream);
    hist_kernel<<<edgeBlocks, blk, 0, stream>>>(ei, deg, E);
    scan1_kernel<<<nodeBlocks, blk, 0, stream>>>(deg, rp, bsum, N);
    scan2_kernel<<<1, 1024, 0, stream>>>(bsum, boff, nodeBlocks);
    scan3_kernel<<<nodeBlocks, blk, 0, stream>>>(rp, wp, boff, N, E);
    csr_scatter_kernel<<<edgeBlocks, blk, 0, stream>>>(ei, eattr, wp, col, eas, E);

    consts_kernel<<<1, 64, 0, stream>>>(w_ee, b_ee, w_eg, att_edge, c1, c0);

    // -------- encoder: hid = relu(x@w1+b1); h = hid@w2+b2 --------
    encode1_kernel<<<nodeWaveBlocks, blk, 0, stream>>>(x, w_ne1, b_ne1, hw, N);
    mm64_kernel<false, true><<<mmBlocks, blk, 0, stream>>>(
        hw, w_ne2, b_ne2, nullptr, nullptr, h, nullptr, nullptr, N);

    // layer-0 transform
    mm64_kernel<true, false><<<mmBlocks, blk, 0, stream>>>(
        h, w_gat, nullptr, att_src, att_dst, hw, a_s, a_d, N);

    for (int l = 0; l < 3; l++) {
        gat_fused_kernel<<<nodeWaveBlocks, blk, 0, stream>>>(
            rp, col, eas, hw, a_s, a_d, c1 + l * 4, c0 + l * 4,
            h, b_gat + l * 64, ln_g + l * 64, ln_b + l * 64, N);
        if (l < 2) {
            mm64_kernel<true, false><<<mmBlocks, blk, 0, stream>>>(
                h, w_gat + (size_t)(l + 1) * 4096, nullptr,
                att_src + (l + 1) * 64, att_dst + (l + 1) * 64,
                hw, a_s, a_d, N);
        }
    }
    // -------- output projection --------
    mm64_kernel<false, true><<<mmBlocks, blk, 0, stream>>>(
        h, w_out, b_out, nullptr, nullptr, (float*)d_out, nullptr, nullptr, N);
}

// Round 7
// 570.863 us; speedup vs baseline: 4.6831x; 1.1134x over previous
//
#include <hip/hip_runtime.h>
#include <hip/hip_bf16.h>

#define NIN 6
#define HIDN 64
#define NHEAD 4

// ---- bf16 pack/unpack (RNE) ----
__device__ __forceinline__ unsigned short f2bf(float f) {
    unsigned u = __float_as_uint(f);
    unsigned r = (u >> 16) & 1u;
    return (unsigned short)((u + 0x7fffu + r) >> 16);
}
__device__ __forceinline__ float bf2f(unsigned short s) {
    return __uint_as_float(((unsigned)s) << 16);
}

// ========== encoder stage 1: hid = relu(x@w1 + b1), wave per node ==========
__global__ __launch_bounds__(256) void encode1_kernel(
    const float* __restrict__ x,
    const float* __restrict__ w1, const float* __restrict__ b1,
    float* __restrict__ hid, int N) {
    int t = blockIdx.x * blockDim.x + threadIdx.x;
    int n = t >> 6, j = t & 63;
    if (n >= N) return;
    float acc = b1[j];
#pragma unroll
    for (int i = 0; i < NIN; i++) acc += x[n * NIN + i] * w1[i * HIDN + j];
    hid[(size_t)n * HIDN + j] = acc > 0.f ? acc : 0.f;
}

// ===== 64x64 fp32 matmul, weight-stationary, wave-uniform row (fp32 out) ====
__global__ __launch_bounds__(256) void mm64_plain_kernel(
    const float* __restrict__ src, const float* __restrict__ W,
    const float* __restrict__ bias, float* __restrict__ dst, int N) {
    int j = threadIdx.x & 63;
    int wv = (blockIdx.x * blockDim.x + threadIdx.x) >> 6;
    int nw = (gridDim.x * blockDim.x) >> 6;

    float Wc[HIDN];
#pragma unroll
    for (int k = 0; k < HIDN; k++) Wc[k] = W[k * HIDN + j];
    float bj = bias[j];

    for (int n0 = wv; n0 < N; n0 += nw) {
        int n = __builtin_amdgcn_readfirstlane(n0);
        const float4* __restrict__ row = (const float4*)(src + (size_t)n * HIDN);
        float a0 = 0.f, a1 = 0.f, a2 = 0.f, a3 = 0.f;
#pragma unroll
        for (int kk = 0; kk < 16; kk++) {
            float4 r = row[kk];
            a0 += r.x * Wc[4 * kk];
            a1 += r.y * Wc[4 * kk + 1];
            a2 += r.z * Wc[4 * kk + 2];
            a3 += r.w * Wc[4 * kk + 3];
        }
        dst[(size_t)n * HIDN + j] = ((a0 + a1) + (a2 + a3)) + bj;
    }
}

// ===== same matmul, bf16 out (gather buffer) + a_s/a_d head dots ===========
__global__ __launch_bounds__(256) void mm64_attn_kernel(
    const float* __restrict__ src, const float* __restrict__ W,
    const float* __restrict__ att_s, const float* __restrict__ att_d,
    unsigned short* __restrict__ dst16,
    float* __restrict__ a_s, float* __restrict__ a_d, int N) {
    int j = threadIdx.x & 63;
    int wv = (blockIdx.x * blockDim.x + threadIdx.x) >> 6;
    int nw = (gridDim.x * blockDim.x) >> 6;

    float Wc[HIDN];
#pragma unroll
    for (int k = 0; k < HIDN; k++) Wc[k] = W[k * HIDN + j];
    float asj = att_s[j];
    float adj = att_d[j];

    for (int n0 = wv; n0 < N; n0 += nw) {
        int n = __builtin_amdgcn_readfirstlane(n0);
        const float4* __restrict__ row = (const float4*)(src + (size_t)n * HIDN);
        float a0 = 0.f, a1 = 0.f, a2 = 0.f, a3 = 0.f;
#pragma unroll
        for (int kk = 0; kk < 16; kk++) {
            float4 r = row[kk];
            a0 += r.x * Wc[4 * kk];
            a1 += r.y * Wc[4 * kk + 1];
            a2 += r.z * Wc[4 * kk + 2];
            a3 += r.w * Wc[4 * kk + 3];
        }
        float acc = (a0 + a1) + (a2 + a3);
        dst16[(size_t)n * HIDN + j] = f2bf(acc);
        float ts = acc * asj;
        float td = acc * adj;
#pragma unroll
        for (int o = 8; o > 0; o >>= 1) {
            ts += __shfl_xor(ts, o);
            td += __shfl_xor(td, o);
        }
        if ((j & 15) == 0) {
            a_s[(size_t)n * NHEAD + (j >> 4)] = ts;
            a_d[(size_t)n * NHEAD + (j >> 4)] = td;
        }
    }
}

// ====== tiny per-layer edge-attn constants: a_e[i,h] = eattr[i]*c1 + c0 =====
__global__ void consts_kernel(const float* __restrict__ w_ee, const float* __restrict__ b_ee,
                              const float* __restrict__ w_eg, const float* __restrict__ att_edge,
                              float* __restrict__ c1, float* __restrict__ c0) {
    int t = threadIdx.x;
    if (t >= 12) return;
    int l = t >> 2, hh = t & 3;
    float s1 = 0.f, s0 = 0.f;
    for (int j = 0; j < HIDN; j++) {
        float wj = 0.f;
        for (int d = 0; d < 16; d++)
            wj += w_eg[l * 4096 + j * 64 + hh * 16 + d] * att_edge[l * 64 + hh * 16 + d];
        s1 += w_ee[j] * wj;
        s0 += b_ee[j] * wj;
    }
    c1[l * 4 + hh] = s1;
    c0[l * 4 + hh] = s0;
}

// ======= CSR build: histogram(+rank) -> scan -> atomic-free scatter =========
__global__ __launch_bounds__(256) void hist_kernel(const int* __restrict__ ei,
                                                   unsigned* __restrict__ deg,
                                                   unsigned* __restrict__ rank, int E) {
    int e = blockIdx.x * 256 + threadIdx.x;
    if (e < E) rank[e] = atomicAdd(&deg[ei[E + e]], 1u);
}

__global__ __launch_bounds__(256) void scan1_kernel(const unsigned* __restrict__ deg,
                                                    unsigned* __restrict__ rp,
                                                    unsigned* __restrict__ bsum, int N) {
    __shared__ unsigned sm[256];
    int t = threadIdx.x, i = blockIdx.x * 256 + t;
    unsigned v = (i < N) ? deg[i] : 0u;
    sm[t] = v;
    __syncthreads();
    unsigned x = v;
    for (int o = 1; o < 256; o <<= 1) {
        unsigned add = (t >= o) ? sm[t - o] : 0u;
        __syncthreads();
        x += add; sm[t] = x;
        __syncthreads();
    }
    if (i < N) rp[i] = x - v;
    if (t == 255) bsum[blockIdx.x] = x;
}

__global__ void scan2_kernel(const unsigned* __restrict__ bsum,
                             unsigned* __restrict__ boff, int nb) {
    __shared__ unsigned sm[1024];
    int t = threadIdx.x;
    unsigned v = (t < nb) ? bsum[t] : 0u;
    sm[t] = v;
    __syncthreads();
    unsigned x = v;
    for (int o = 1; o < 1024; o <<= 1) {
        unsigned add = (t >= o) ? sm[t - o] : 0u;
        __syncthreads();
        x += add; sm[t] = x;
        __syncthreads();
    }
    if (t < nb) boff[t] = x - v;
}

__global__ __launch_bounds__(256) void scan3_kernel(unsigned* __restrict__ rp,
                                                    const unsigned* __restrict__ boff,
                                                    int N, int E) {
    int i = blockIdx.x * 256 + threadIdx.x;
    if (i < N) rp[i] = rp[i] + boff[blockIdx.x];
    if (i == 0) rp[N] = (unsigned)E;
}

// one packed 8B store per edge; no atomics
__global__ __launch_bounds__(256) void csr_scatter_kernel(
    const int* __restrict__ ei, const float* __restrict__ eattr,
    const unsigned* __restrict__ rp, const unsigned* __restrict__ rank,
    int2* __restrict__ eca, int E) {
    int e = blockIdx.x * 256 + threadIdx.x;
    if (e >= E) return;
    int s = ei[e], d = ei[E + e];
    unsigned p = rp[d] + rank[e];
    eca[p] = make_int2(s, __float_as_int(eattr[e]));
}

// ===== fused per-layer edge pipeline: wave per dst node ====================
// score -> transposed-LDS online softmax -> x4-unrolled weighted agg of
// bf16 hw[src] -> bias/ELU/residual/LayerNorm -> write h. No atomics.
__global__ __launch_bounds__(256) void gat_fused_kernel(
    const unsigned* __restrict__ rp, const int2* __restrict__ eca,
    const unsigned short* __restrict__ hw16,
    const float* __restrict__ a_s, const float* __restrict__ a_d,
    const float* __restrict__ c1, const float* __restrict__ c0,
    float* __restrict__ h, const float* __restrict__ bg,
    const float* __restrict__ g, const float* __restrict__ b, int N) {
    __shared__ float exl[4 * 256];   // per wave: 64 edges x 4 heads
    int t = blockIdx.x * blockDim.x + threadIdx.x;
    int n = t >> 6, j = t & 63;
    if (n >= N) return;
    int hh = j >> 4;
    int l16 = j & 15;
    float* myex = exl + ((threadIdx.x >> 6) << 8);

    unsigned beg = rp[n];
    int deg = (int)(rp[n + 1] - beg);

    float4 ad4 = *(const float4*)(a_d + (size_t)n * 4);
    float4 C1 = *(const float4*)c1;
    float4 C0 = *(const float4*)c0;

    float m = -1e30f, ssum = 0.f;
    float accA = 0.f, accB = 0.f, accC = 0.f, accD = 0.f;

    for (int cs = 0; cs < deg; cs += 64) {
        int i = cs + j;
        bool act = i < deg;
        int2 ce = act ? eca[beg + i] : make_int2(0, 0);
        int src = ce.x;
        float ea = __int_as_float(ce.y);
        float sc0 = -1e30f, sc1 = -1e30f, sc2 = -1e30f, sc3 = -1e30f;
        if (act) {
            float4 as4 = *(const float4*)(a_s + (size_t)src * 4);
            sc0 = as4.x + ad4.x + ea * C1.x + C0.x;
            sc1 = as4.y + ad4.y + ea * C1.y + C0.y;
            sc2 = as4.z + ad4.z + ea * C1.z + C0.z;
            sc3 = as4.w + ad4.w + ea * C1.w + C0.w;
            sc0 = sc0 >= 0.f ? sc0 : 0.2f * sc0;
            sc1 = sc1 >= 0.f ? sc1 : 0.2f * sc1;
            sc2 = sc2 >= 0.f ? sc2 : 0.2f * sc2;
            sc3 = sc3 >= 0.f ? sc3 : 0.2f * sc3;
        }
        *(float4*)(myex + (j << 2)) = make_float4(sc0, sc1, sc2, sc3);

        int cl = deg - cs; if (cl > 64) cl = 64;
        float s0 = myex[((l16     ) << 2) + hh];
        float s1 = myex[((l16 + 16) << 2) + hh];
        float s2 = myex[((l16 + 32) << 2) + hh];
        float s3 = myex[((l16 + 48) << 2) + hh];
        float cmax = fmaxf(fmaxf(s0, s1), fmaxf(s2, s3));
#pragma unroll
        for (int o = 8; o > 0; o >>= 1) cmax = fmaxf(cmax, __shfl_xor(cmax, o));
        float nm = fmaxf(m, cmax);
        float r = __expf(m - nm);
        m = nm;
        float e0 = (l16      < cl) ? __expf(s0 - nm) : 0.f;
        float e1 = (l16 + 16 < cl) ? __expf(s1 - nm) : 0.f;
        float e2 = (l16 + 32 < cl) ? __expf(s2 - nm) : 0.f;
        float e3 = (l16 + 48 < cl) ? __expf(s3 - nm) : 0.f;
        myex[((l16     ) << 2) + hh] = e0;
        myex[((l16 + 16) << 2) + hh] = e1;
        myex[((l16 + 32) << 2) + hh] = e2;
        myex[((l16 + 48) << 2) + hh] = e3;
        float csum = (e0 + e1) + (e2 + e3);
#pragma unroll
        for (int o = 8; o > 0; o >>= 1) csum += __shfl_xor(csum, o);
        ssum = ssum * r + csum;
        accA *= r; accB *= r; accC *= r; accD *= r;

        for (int i2 = 0; i2 < cl; i2 += 4) {
            int sA = __shfl(src, i2);
            int sB = __shfl(src, i2 + 1);
            int sC = __shfl(src, i2 + 2);
            int sD = __shfl(src, i2 + 3);
            float wA = myex[((i2    ) << 2) + hh];
            float wB = myex[((i2 + 1) << 2) + hh];
            float wC = myex[((i2 + 2) << 2) + hh];
            float wD = myex[((i2 + 3) << 2) + hh];
            float vA = bf2f(hw16[(size_t)sA * HIDN + j]);
            float vB = bf2f(hw16[(size_t)sB * HIDN + j]);
            float vC = bf2f(hw16[(size_t)sC * HIDN + j]);
            float vD = bf2f(hw16[(size_t)sD * HIDN + j]);
            accA += wA * vA;
            accB += wB * vB;
            accC += wC * vC;
            accD += wD * vD;
        }
    }
    float agg = ((accA + accB) + (accC + accD)) / (ssum + 1e-16f);

    // epilogue: h = LN(h + elu(agg + bg))
    float a = agg + bg[j];
    float el = a > 0.f ? a : (__expf(a) - 1.f);
    float v = h[(size_t)n * HIDN + j] + el;
    float s = v, sq = v * v;
#pragma unroll
    for (int o = 32; o > 0; o >>= 1) {
        s += __shfl_xor(s, o);
        sq += __shfl_xor(sq, o);
    }
    float mean = s * (1.f / 64.f);
    float var = sq * (1.f / 64.f) - mean * mean;
    float rr = rsqrtf(var + 1e-5f);
    h[(size_t)n * HIDN + j] = (v - mean) * rr * g[j] + b[j];
}

extern "C" void kernel_launch(void* const* d_in, const int* in_sizes, int n_in,
                              void* d_out, int out_size, void* d_ws, size_t ws_size,
                              hipStream_t stream) {
    const float* x      = (const float*)d_in[0];
    const int*   ei     = (const int*)d_in[1];
    const float* eattr  = (const float*)d_in[2];
    const float* w_ne1  = (const float*)d_in[3];
    const float* b_ne1  = (const float*)d_in[4];
    const float* w_ne2  = (const float*)d_in[5];
    const float* b_ne2  = (const float*)d_in[6];
    const float* w_ee   = (const float*)d_in[7];
    const float* b_ee   = (const float*)d_in[8];
    const float* w_gat  = (const float*)d_in[9];
    const float* w_eg   = (const float*)d_in[10];
    const float* att_src= (const float*)d_in[11];
    const float* att_dst= (const float*)d_in[12];
    const float* att_edge=(const float*)d_in[13];
    const float* b_gat  = (const float*)d_in[14];
    const float* ln_g   = (const float*)d_in[15];
    const float* ln_b   = (const float*)d_in[16];
    const float* w_out  = (const float*)d_in[17];
    const float* b_out  = (const float*)d_in[18];

    const int N = in_sizes[0] / NIN;
    const int E = in_sizes[2];

    // -------- workspace layout --------
    float* ws   = (float*)d_ws;
    float* h    = ws;                                   // N*64
    float* hid  = h + (size_t)N * 64;                   // N*64
    unsigned short* hw16 = (unsigned short*)(hid + (size_t)N * 64);  // N*64 u16
    float* a_s  = (float*)(hw16 + (size_t)N * 64);      // N*4
    float* a_d  = a_s + (size_t)N * 4;                  // N*4
    float* c1   = a_d + (size_t)N * 4;                  // 12
    float* c0   = c1 + 12;                              // 12
    int2*  eca  = (int2*)(c0 + 12);                     // E int2
    unsigned* rank = (unsigned*)(eca + (size_t)E);      // E
    unsigned* deg  = rank + (size_t)E;                  // N
    unsigned* rp   = deg + (size_t)N;                   // N+1
    unsigned* bsum = rp + (size_t)N + 1;                // <=1024
    unsigned* boff = bsum + 1024;                       // <=1024

    dim3 blk(256);
    int nodeWaveBlocks = (int)(((size_t)N * 64 + 255) / 256);
    int edgeBlocks = (E + 255) / 256;
    int nodeBlocks = (N + 255) / 256;
    int mmBlocks = 2048;    // 8192 waves, grid-stride over nodes

    // -------- CSR build (rank from hist atomic; scatter atomic-free) -------
    hipMemsetAsync(deg, 0, (size_t)N * sizeof(unsigned), stream);
    hist_kernel<<<edgeBlocks, blk, 0, stream>>>(ei, deg, rank, E);
    scan1_kernel<<<nodeBlocks, blk, 0, stream>>>(deg, rp, bsum, N);
    scan2_kernel<<<1, 1024, 0, stream>>>(bsum, boff, nodeBlocks);
    scan3_kernel<<<nodeBlocks, blk, 0, stream>>>(rp, boff, N, E);
    csr_scatter_kernel<<<edgeBlocks, blk, 0, stream>>>(ei, eattr, rp, rank, eca, E);

    consts_kernel<<<1, 64, 0, stream>>>(w_ee, b_ee, w_eg, att_edge, c1, c0);

    // -------- encoder: hid = relu(x@w1+b1); h = hid@w2+b2 --------
    encode1_kernel<<<nodeWaveBlocks, blk, 0, stream>>>(x, w_ne1, b_ne1, hid, N);
    mm64_plain_kernel<<<mmBlocks, blk, 0, stream>>>(hid, w_ne2, b_ne2, h, N);

    // layer-0 transform
    mm64_attn_kernel<<<mmBlocks, blk, 0, stream>>>(
        h, w_gat, att_src, att_dst, hw16, a_s, a_d, N);

    for (int l = 0; l < 3; l++) {
        gat_fused_kernel<<<nodeWaveBlocks, blk, 0, stream>>>(
            rp, eca, hw16, a_s, a_d, c1 + l * 4, c0 + l * 4,
            h, b_gat + l * 64, ln_g + l * 64, ln_b + l * 64, N);
        if (l < 2) {
            mm64_attn_kernel<<<mmBlocks, blk, 0, stream>>>(
                h, w_gat + (size_t)(l + 1) * 4096,
                att_src + (l + 1) * 64, att_dst + (l + 1) * 64,
                hw16, a_s, a_d, N);
        }
    }
    // -------- output projection --------
    mm64_plain_kernel<<<mmBlocks, blk, 0, stream>>>(h, w_out, b_out, (float*)d_out, N);
}

// Round 8
// 506.187 us; speedup vs baseline: 5.2815x; 1.1278x over previous
//
#include <hip/hip_runtime.h>
#include <hip/hip_bf16.h>

#define NIN 6
#define HIDN 64
#define NHEAD 4

// ---- bf16 pack (RNE) ----
__device__ __forceinline__ unsigned short f2bf(float f) {
    unsigned u = __float_as_uint(f);
    unsigned r = (u >> 16) & 1u;
    return (unsigned short)((u + 0x7fffu + r) >> 16);
}

// ========== encoder stage 1: hid = relu(x@w1 + b1), wave per node ==========
__global__ __launch_bounds__(256) void encode1_kernel(
    const float* __restrict__ x,
    const float* __restrict__ w1, const float* __restrict__ b1,
    float* __restrict__ hid, int N) {
    int t = blockIdx.x * blockDim.x + threadIdx.x;
    int n = t >> 6, j = t & 63;
    if (n >= N) return;
    float acc = b1[j];
#pragma unroll
    for (int i = 0; i < NIN; i++) acc += x[n * NIN + i] * w1[i * HIDN + j];
    hid[(size_t)n * HIDN + j] = acc > 0.f ? acc : 0.f;
}

// ===== 64x64 fp32 matmul, weight-stationary, wave-uniform row (fp32 out) ====
__global__ __launch_bounds__(256) void mm64_plain_kernel(
    const float* __restrict__ src, const float* __restrict__ W,
    const float* __restrict__ bias, float* __restrict__ dst, int N) {
    int j = threadIdx.x & 63;
    int wv = (blockIdx.x * blockDim.x + threadIdx.x) >> 6;
    int nw = (gridDim.x * blockDim.x) >> 6;

    float Wc[HIDN];
#pragma unroll
    for (int k = 0; k < HIDN; k++) Wc[k] = W[k * HIDN + j];
    float bj = bias[j];

    for (int n0 = wv; n0 < N; n0 += nw) {
        int n = __builtin_amdgcn_readfirstlane(n0);
        const float4* __restrict__ row = (const float4*)(src + (size_t)n * HIDN);
        float a0 = 0.f, a1 = 0.f, a2 = 0.f, a3 = 0.f;
#pragma unroll
        for (int kk = 0; kk < 16; kk++) {
            float4 r = row[kk];
            a0 += r.x * Wc[4 * kk];
            a1 += r.y * Wc[4 * kk + 1];
            a2 += r.z * Wc[4 * kk + 2];
            a3 += r.w * Wc[4 * kk + 3];
        }
        dst[(size_t)n * HIDN + j] = ((a0 + a1) + (a2 + a3)) + bj;
    }
}

// ===== same matmul, bf16 out (gather buffer) + a_s/a_d head dots ===========
__global__ __launch_bounds__(256) void mm64_attn_kernel(
    const float* __restrict__ src, const float* __restrict__ W,
    const float* __restrict__ att_s, const float* __restrict__ att_d,
    unsigned short* __restrict__ dst16,
    float* __restrict__ a_s, float* __restrict__ a_d, int N) {
    int j = threadIdx.x & 63;
    int wv = (blockIdx.x * blockDim.x + threadIdx.x) >> 6;
    int nw = (gridDim.x * blockDim.x) >> 6;

    float Wc[HIDN];
#pragma unroll
    for (int k = 0; k < HIDN; k++) Wc[k] = W[k * HIDN + j];
    float asj = att_s[j];
    float adj = att_d[j];

    for (int n0 = wv; n0 < N; n0 += nw) {
        int n = __builtin_amdgcn_readfirstlane(n0);
        const float4* __restrict__ row = (const float4*)(src + (size_t)n * HIDN);
        float a0 = 0.f, a1 = 0.f, a2 = 0.f, a3 = 0.f;
#pragma unroll
        for (int kk = 0; kk < 16; kk++) {
            float4 r = row[kk];
            a0 += r.x * Wc[4 * kk];
            a1 += r.y * Wc[4 * kk + 1];
            a2 += r.z * Wc[4 * kk + 2];
            a3 += r.w * Wc[4 * kk + 3];
        }
        float acc = (a0 + a1) + (a2 + a3);
        dst16[(size_t)n * HIDN + j] = f2bf(acc);
        float ts = acc * asj;
        float td = acc * adj;
#pragma unroll
        for (int o = 8; o > 0; o >>= 1) {
            ts += __shfl_xor(ts, o);
            td += __shfl_xor(td, o);
        }
        if ((j & 15) == 0) {
            a_s[(size_t)n * NHEAD + (j >> 4)] = ts;
            a_d[(size_t)n * NHEAD + (j >> 4)] = td;
        }
    }
}

// ====== tiny per-layer edge-attn constants: a_e[i,h] = eattr[i]*c1 + c0 =====
__global__ void consts_kernel(const float* __restrict__ w_ee, const float* __restrict__ b_ee,
                              const float* __restrict__ w_eg, const float* __restrict__ att_edge,
                              float* __restrict__ c1, float* __restrict__ c0) {
    int t = threadIdx.x;
    if (t >= 12) return;
    int l = t >> 2, hh = t & 3;
    float s1 = 0.f, s0 = 0.f;
    for (int j = 0; j < HIDN; j++) {
        float wj = 0.f;
        for (int d = 0; d < 16; d++)
            wj += w_eg[l * 4096 + j * 64 + hh * 16 + d] * att_edge[l * 64 + hh * 16 + d];
        s1 += w_ee[j] * wj;
        s0 += b_ee[j] * wj;
    }
    c1[l * 4 + hh] = s1;
    c0[l * 4 + hh] = s0;
}

// ======= CSR build: histogram(+rank) -> scan -> atomic-free scatter =========
__global__ __launch_bounds__(256) void hist_kernel(const int* __restrict__ ei,
                                                   unsigned* __restrict__ deg,
                                                   unsigned* __restrict__ rank, int E) {
    int e = blockIdx.x * 256 + threadIdx.x;
    if (e < E) rank[e] = atomicAdd(&deg[ei[E + e]], 1u);
}

__global__ __launch_bounds__(256) void scan1_kernel(const unsigned* __restrict__ deg,
                                                    unsigned* __restrict__ rp,
                                                    unsigned* __restrict__ bsum, int N) {
    __shared__ unsigned sm[256];
    int t = threadIdx.x, i = blockIdx.x * 256 + t;
    unsigned v = (i < N) ? deg[i] : 0u;
    sm[t] = v;
    __syncthreads();
    unsigned x = v;
    for (int o = 1; o < 256; o <<= 1) {
        unsigned add = (t >= o) ? sm[t - o] : 0u;
        __syncthreads();
        x += add; sm[t] = x;
        __syncthreads();
    }
    if (i < N) rp[i] = x - v;
    if (t == 255) bsum[blockIdx.x] = x;
}

__global__ void scan2_kernel(const unsigned* __restrict__ bsum,
                             unsigned* __restrict__ boff, int nb) {
    __shared__ unsigned sm[1024];
    int t = threadIdx.x;
    unsigned v = (t < nb) ? bsum[t] : 0u;
    sm[t] = v;
    __syncthreads();
    unsigned x = v;
    for (int o = 1; o < 1024; o <<= 1) {
        unsigned add = (t >= o) ? sm[t - o] : 0u;
        __syncthreads();
        x += add; sm[t] = x;
        __syncthreads();
    }
    if (t < nb) boff[t] = x - v;
}

__global__ __launch_bounds__(256) void scan3_kernel(unsigned* __restrict__ rp,
                                                    const unsigned* __restrict__ boff,
                                                    int N, int E) {
    int i = blockIdx.x * 256 + threadIdx.x;
    if (i < N) rp[i] = rp[i] + boff[blockIdx.x];
    if (i == 0) rp[N] = (unsigned)E;
}

// one packed 8B store per edge; no atomics
__global__ __launch_bounds__(256) void csr_scatter_kernel(
    const int* __restrict__ ei, const float* __restrict__ eattr,
    const unsigned* __restrict__ rp, const unsigned* __restrict__ rank,
    int2* __restrict__ eca, int E) {
    int e = blockIdx.x * 256 + threadIdx.x;
    if (e >= E) return;
    int s = ei[e], d = ei[E + e];
    unsigned p = rp[d] + rank[e];
    eca[p] = make_int2(s, __float_as_int(eattr[e]));
}

// ===== fused per-layer edge pipeline: 4 dst nodes per wave =================
// 16 lanes/node (quad), 4 channels/lane. score -> exp (no max-subtract:
// mathematically identical softmax, scores are O(1)) -> den via quad
// reduction -> fully-unrolled 16-edge weighted agg of bf16 hw rows (uint2
// gathers, LDS-broadcast weights/srcs) -> bias/ELU/residual/LN -> write h.
__global__ __launch_bounds__(256) void gat_fused_kernel(
    const unsigned* __restrict__ rp, const int2* __restrict__ eca,
    const unsigned short* __restrict__ hw16,
    const float* __restrict__ a_s, const float* __restrict__ a_d,
    const float* __restrict__ c1, const float* __restrict__ c0,
    float* __restrict__ h, const float* __restrict__ bg,
    const float* __restrict__ g, const float* __restrict__ b, int N) {
    // per-wave LDS: ex[4 quads][68 words pad], src[4 quads][17 words pad]
    __shared__ float exl[4 * 272];
    __shared__ int srl[4 * 68];
    int t = blockIdx.x * blockDim.x + threadIdx.x;
    int lane = t & 63;
    int q = lane >> 4;        // quad = which of the 4 nodes
    int l = lane & 15;        // lane within quad
    int hd = l >> 2;          // head owned by this lane (channels 4l..4l+3)
    int sub = l & 3;
    int n = ((t >> 6) << 2) + q;
    int wslot = (threadIdx.x >> 6);
    float* myex = exl + wslot * 272 + 68 * q;
    int* mysrc = srl + wslot * 68 + 17 * q;

    bool nv = n < N;
    unsigned beg = nv ? rp[n] : 0u;
    int deg = nv ? (int)(rp[n + 1] - beg) : 0;

    float4 ad4 = nv ? *(const float4*)(a_d + ((size_t)n << 2)) : make_float4(0, 0, 0, 0);
    float4 C1 = *(const float4*)c1;
    float4 C0 = *(const float4*)c0;

    int md = deg;
    md = max(md, __shfl_xor(md, 16));
    md = max(md, __shfl_xor(md, 32));
    int chunks = (md + 15) >> 4;

    const unsigned* __restrict__ hwp = (const unsigned*)hw16;
    unsigned loff = (unsigned)(l << 1);   // uint offset within row

    float ssum = 0.f;
    float ac0 = 0.f, ac1 = 0.f, ac2 = 0.f, ac3 = 0.f;

    for (int k = 0; k < chunks; k++) {
        int i = (k << 4) + l;
        bool act = i < deg;
        int2 ce = act ? eca[beg + i] : make_int2(0, 0);
        int src = ce.x;
        float ea = __int_as_float(ce.y);
        float4 as4 = act ? *(const float4*)(a_s + ((size_t)src << 2))
                         : make_float4(0, 0, 0, 0);
        float s0 = as4.x + ad4.x + ea * C1.x + C0.x;
        float s1 = as4.y + ad4.y + ea * C1.y + C0.y;
        float s2 = as4.z + ad4.z + ea * C1.z + C0.z;
        float s3 = as4.w + ad4.w + ea * C1.w + C0.w;
        s0 = s0 >= 0.f ? s0 : 0.2f * s0;
        s1 = s1 >= 0.f ? s1 : 0.2f * s1;
        s2 = s2 >= 0.f ? s2 : 0.2f * s2;
        s3 = s3 >= 0.f ? s3 : 0.2f * s3;
        float e0 = act ? __expf(s0) : 0.f;
        float e1 = act ? __expf(s1) : 0.f;
        float e2 = act ? __expf(s2) : 0.f;
        float e3 = act ? __expf(s3) : 0.f;
        *(float4*)(myex + (l << 2)) = make_float4(e0, e1, e2, e3);
        mysrc[l] = act ? src : 0;

        // den partial for owned head: edges sub, sub+4, sub+8, sub+12
        float w0 = myex[(sub << 2) + hd];
        float w1 = myex[((sub + 4) << 2) + hd];
        float w2 = myex[((sub + 8) << 2) + hd];
        float w3 = myex[((sub + 12) << 2) + hd];
        float csum = (w0 + w1) + (w2 + w3);
        csum += __shfl_xor(csum, 1);
        csum += __shfl_xor(csum, 2);
        ssum += csum;

        // fully-unrolled 16-edge aggregation (zero-weight padding is safe)
#pragma unroll
        for (int e = 0; e < 16; e++) {
            float w = myex[(e << 2) + hd];
            int so = mysrc[e];
            uint2 uu = *(const uint2*)(hwp + (((unsigned)so << 5) + loff));
            ac0 += w * __uint_as_float(uu.x << 16);
            ac1 += w * __uint_as_float(uu.x & 0xffff0000u);
            ac2 += w * __uint_as_float(uu.y << 16);
            ac3 += w * __uint_as_float(uu.y & 0xffff0000u);
        }
    }

    if (!nv) return;
    float inv = 1.f / (ssum + 1e-16f);
    float4 bg4 = *(const float4*)(bg + (l << 2));
    float4 hv4 = *(const float4*)(h + (size_t)n * HIDN + (l << 2));

    float a0 = ac0 * inv + bg4.x;
    float a1 = ac1 * inv + bg4.y;
    float a2 = ac2 * inv + bg4.z;
    float a3 = ac3 * inv + bg4.w;
    a0 = a0 > 0.f ? a0 : (__expf(a0) - 1.f);
    a1 = a1 > 0.f ? a1 : (__expf(a1) - 1.f);
    a2 = a2 > 0.f ? a2 : (__expf(a2) - 1.f);
    a3 = a3 > 0.f ? a3 : (__expf(a3) - 1.f);
    float v0 = hv4.x + a0, v1 = hv4.y + a1, v2 = hv4.z + a2, v3 = hv4.w + a3;

    float s = (v0 + v1) + (v2 + v3);
    float sq = (v0 * v0 + v1 * v1) + (v2 * v2 + v3 * v3);
#pragma unroll
    for (int o = 8; o > 0; o >>= 1) {
        s += __shfl_xor(s, o);
        sq += __shfl_xor(sq, o);
    }
    float mean = s * (1.f / 64.f);
    float var = sq * (1.f / 64.f) - mean * mean;
    float rr = rsqrtf(var + 1e-5f);
    float4 g4 = *(const float4*)(g + (l << 2));
    float4 b4 = *(const float4*)(b + (l << 2));
    float4 outv;
    outv.x = (v0 - mean) * rr * g4.x + b4.x;
    outv.y = (v1 - mean) * rr * g4.y + b4.y;
    outv.z = (v2 - mean) * rr * g4.z + b4.z;
    outv.w = (v3 - mean) * rr * g4.w + b4.w;
    *(float4*)(h + (size_t)n * HIDN + (l << 2)) = outv;
}

extern "C" void kernel_launch(void* const* d_in, const int* in_sizes, int n_in,
                              void* d_out, int out_size, void* d_ws, size_t ws_size,
                              hipStream_t stream) {
    const float* x      = (const float*)d_in[0];
    const int*   ei     = (const int*)d_in[1];
    const float* eattr  = (const float*)d_in[2];
    const float* w_ne1  = (const float*)d_in[3];
    const float* b_ne1  = (const float*)d_in[4];
    const float* w_ne2  = (const float*)d_in[5];
    const float* b_ne2  = (const float*)d_in[6];
    const float* w_ee   = (const float*)d_in[7];
    const float* b_ee   = (const float*)d_in[8];
    const float* w_gat  = (const float*)d_in[9];
    const float* w_eg   = (const float*)d_in[10];
    const float* att_src= (const float*)d_in[11];
    const float* att_dst= (const float*)d_in[12];
    const float* att_edge=(const float*)d_in[13];
    const float* b_gat  = (const float*)d_in[14];
    const float* ln_g   = (const float*)d_in[15];
    const float* ln_b   = (const float*)d_in[16];
    const float* w_out  = (const float*)d_in[17];
    const float* b_out  = (const float*)d_in[18];

    const int N = in_sizes[0] / NIN;
    const int E = in_sizes[2];

    // -------- workspace layout --------
    float* ws   = (float*)d_ws;
    float* h    = ws;                                   // N*64
    float* hid  = h + (size_t)N * 64;                   // N*64
    unsigned short* hw16 = (unsigned short*)(hid + (size_t)N * 64);  // N*64 u16
    float* a_s  = (float*)(hw16 + (size_t)N * 64);      // N*4
    float* a_d  = a_s + (size_t)N * 4;                  // N*4
    float* c1   = a_d + (size_t)N * 4;                  // 12
    float* c0   = c1 + 12;                              // 12
    int2*  eca  = (int2*)(c0 + 12);                     // E int2
    unsigned* rank = (unsigned*)(eca + (size_t)E);      // E
    unsigned* deg  = rank + (size_t)E;                  // N
    unsigned* rp   = deg + (size_t)N;                   // N+1
    unsigned* bsum = rp + (size_t)N + 1;                // <=1024
    unsigned* boff = bsum + 1024;                       // <=1024

    dim3 blk(256);
    int nodeWaveBlocks = (int)(((size_t)N * 64 + 255) / 256);
    int quadBlocks = (int)(((size_t)((N + 3) / 4) * 64 + 255) / 256);
    int edgeBlocks = (E + 255) / 256;
    int nodeBlocks = (N + 255) / 256;
    int mmBlocks = 2048;    // 8192 waves, grid-stride over nodes

    // -------- CSR build (rank from hist atomic; scatter atomic-free) -------
    hipMemsetAsync(deg, 0, (size_t)N * sizeof(unsigned), stream);
    hist_kernel<<<edgeBlocks, blk, 0, stream>>>(ei, deg, rank, E);
    scan1_kernel<<<nodeBlocks, blk, 0, stream>>>(deg, rp, bsum, N);
    scan2_kernel<<<1, 1024, 0, stream>>>(bsum, boff, nodeBlocks);
    scan3_kernel<<<nodeBlocks, blk, 0, stream>>>(rp, boff, N, E);
    csr_scatter_kernel<<<edgeBlocks, blk, 0, stream>>>(ei, eattr, rp, rank, eca, E);

    consts_kernel<<<1, 64, 0, stream>>>(w_ee, b_ee, w_eg, att_edge, c1, c0);

    // -------- encoder: hid = relu(x@w1+b1); h = hid@w2+b2 --------
    encode1_kernel<<<nodeWaveBlocks, blk, 0, stream>>>(x, w_ne1, b_ne1, hid, N);
    mm64_plain_kernel<<<mmBlocks, blk, 0, stream>>>(hid, w_ne2, b_ne2, h, N);

    // layer-0 transform
    mm64_attn_kernel<<<mmBlocks, blk, 0, stream>>>(
        h, w_gat, att_src, att_dst, hw16, a_s, a_d, N);

    for (int l = 0; l < 3; l++) {
        gat_fused_kernel<<<quadBlocks, blk, 0, stream>>>(
            rp, eca, hw16, a_s, a_d, c1 + l * 4, c0 + l * 4,
            h, b_gat + l * 64, ln_g + l * 64, ln_b + l * 64, N);
        if (l < 2) {
            mm64_attn_kernel<<<mmBlocks, blk, 0, stream>>>(
                h, w_gat + (size_t)(l + 1) * 4096,
                att_src + (l + 1) * 64, att_dst + (l + 1) * 64,
                hw16, a_s, a_d, N);
        }
    }
    // -------- output projection --------
    mm64_plain_kernel<<<mmBlocks, blk, 0, stream>>>(h, w_out, b_out, (float*)d_out, N);
}

// Round 9
// 500.262 us; speedup vs baseline: 5.3441x; 1.0118x over previous
//
#include <hip/hip_runtime.h>
#include <hip/hip_bf16.h>

#define NIN 6
#define HIDN 64
#define NHEAD 4
#define DEGPAD 5   // deg[] stride = 32 words = 128 B: one counter per L2 line

// ---- bf16 pack (RNE) ----
__device__ __forceinline__ unsigned short f2bf(float f) {
    unsigned u = __float_as_uint(f);
    unsigned r = (u >> 16) & 1u;
    return (unsigned short)((u + 0x7fffu + r) >> 16);
}

// ========== encoder stage 1: hid = relu(x@w1 + b1), wave per node ==========
__global__ __launch_bounds__(256) void encode1_kernel(
    const float* __restrict__ x,
    const float* __restrict__ w1, const float* __restrict__ b1,
    float* __restrict__ hid, int N) {
    int t = blockIdx.x * blockDim.x + threadIdx.x;
    int n = t >> 6, j = t & 63;
    if (n >= N) return;
    float acc = b1[j];
#pragma unroll
    for (int i = 0; i < NIN; i++) acc += x[n * NIN + i] * w1[i * HIDN + j];
    hid[(size_t)n * HIDN + j] = acc > 0.f ? acc : 0.f;
}

// ===== 64x64 fp32 matmul, weight-stationary, wave-uniform row (fp32 out) ====
__global__ __launch_bounds__(256) void mm64_plain_kernel(
    const float* __restrict__ src, const float* __restrict__ W,
    const float* __restrict__ bias, float* __restrict__ dst, int N) {
    int j = threadIdx.x & 63;
    int wv = (blockIdx.x * blockDim.x + threadIdx.x) >> 6;
    int nw = (gridDim.x * blockDim.x) >> 6;

    float Wc[HIDN];
#pragma unroll
    for (int k = 0; k < HIDN; k++) Wc[k] = W[k * HIDN + j];
    float bj = bias[j];

    for (int n0 = wv; n0 < N; n0 += nw) {
        int n = __builtin_amdgcn_readfirstlane(n0);
        const float4* __restrict__ row = (const float4*)(src + (size_t)n * HIDN);
        float a0 = 0.f, a1 = 0.f, a2 = 0.f, a3 = 0.f;
#pragma unroll
        for (int kk = 0; kk < 16; kk++) {
            float4 r = row[kk];
            a0 += r.x * Wc[4 * kk];
            a1 += r.y * Wc[4 * kk + 1];
            a2 += r.z * Wc[4 * kk + 2];
            a3 += r.w * Wc[4 * kk + 3];
        }
        dst[(size_t)n * HIDN + j] = ((a0 + a1) + (a2 + a3)) + bj;
    }
}

// ===== same matmul, bf16 out (gather buffer) + a_s/a_d head dots ===========
__global__ __launch_bounds__(256) void mm64_attn_kernel(
    const float* __restrict__ src, const float* __restrict__ W,
    const float* __restrict__ att_s, const float* __restrict__ att_d,
    unsigned short* __restrict__ dst16,
    float* __restrict__ a_s, float* __restrict__ a_d, int N) {
    int j = threadIdx.x & 63;
    int wv = (blockIdx.x * blockDim.x + threadIdx.x) >> 6;
    int nw = (gridDim.x * blockDim.x) >> 6;

    float Wc[HIDN];
#pragma unroll
    for (int k = 0; k < HIDN; k++) Wc[k] = W[k * HIDN + j];
    float asj = att_s[j];
    float adj = att_d[j];

    for (int n0 = wv; n0 < N; n0 += nw) {
        int n = __builtin_amdgcn_readfirstlane(n0);
        const float4* __restrict__ row = (const float4*)(src + (size_t)n * HIDN);
        float a0 = 0.f, a1 = 0.f, a2 = 0.f, a3 = 0.f;
#pragma unroll
        for (int kk = 0; kk < 16; kk++) {
            float4 r = row[kk];
            a0 += r.x * Wc[4 * kk];
            a1 += r.y * Wc[4 * kk + 1];
            a2 += r.z * Wc[4 * kk + 2];
            a3 += r.w * Wc[4 * kk + 3];
        }
        float acc = (a0 + a1) + (a2 + a3);
        dst16[(size_t)n * HIDN + j] = f2bf(acc);
        float ts = acc * asj;
        float td = acc * adj;
#pragma unroll
        for (int o = 8; o > 0; o >>= 1) {
            ts += __shfl_xor(ts, o);
            td += __shfl_xor(td, o);
        }
        if ((j & 15) == 0) {
            a_s[(size_t)n * NHEAD + (j >> 4)] = ts;
            a_d[(size_t)n * NHEAD + (j >> 4)] = td;
        }
    }
}

// ====== tiny per-layer edge-attn constants: a_e[i,h] = eattr[i]*c1 + c0 =====
__global__ void consts_kernel(const float* __restrict__ w_ee, const float* __restrict__ b_ee,
                              const float* __restrict__ w_eg, const float* __restrict__ att_edge,
                              float* __restrict__ c1, float* __restrict__ c0) {
    int t = threadIdx.x;
    if (t >= 12) return;
    int l = t >> 2, hh = t & 3;
    float s1 = 0.f, s0 = 0.f;
    for (int j = 0; j < HIDN; j++) {
        float wj = 0.f;
        for (int d = 0; d < 16; d++)
            wj += w_eg[l * 4096 + j * 64 + hh * 16 + d] * att_edge[l * 64 + hh * 16 + d];
        s1 += w_ee[j] * wj;
        s0 += b_ee[j] * wj;
    }
    c1[l * 4 + hh] = s1;
    c0[l * 4 + hh] = s0;
}

// ======= CSR build: histogram(+rank) -> scan -> atomic-free scatter =========
// deg is line-padded (1 counter / 128B) to kill same-line atomic serialization
__global__ __launch_bounds__(256) void hist_kernel(const int* __restrict__ ei,
                                                   unsigned* __restrict__ deg,
                                                   unsigned* __restrict__ rank, int E) {
    int e = blockIdx.x * 256 + threadIdx.x;
    if (e < E) rank[e] = atomicAdd(&deg[(size_t)ei[E + e] << DEGPAD], 1u);
}

__global__ __launch_bounds__(256) void scan1_kernel(const unsigned* __restrict__ deg,
                                                    unsigned* __restrict__ rp,
                                                    unsigned* __restrict__ bsum, int N) {
    __shared__ unsigned sm[256];
    int t = threadIdx.x, i = blockIdx.x * 256 + t;
    unsigned v = (i < N) ? deg[(size_t)i << DEGPAD] : 0u;
    sm[t] = v;
    __syncthreads();
    unsigned x = v;
    for (int o = 1; o < 256; o <<= 1) {
        unsigned add = (t >= o) ? sm[t - o] : 0u;
        __syncthreads();
        x += add; sm[t] = x;
        __syncthreads();
    }
    if (i < N) rp[i] = x - v;
    if (t == 255) bsum[blockIdx.x] = x;
}

__global__ void scan2_kernel(const unsigned* __restrict__ bsum,
                             unsigned* __restrict__ boff, int nb) {
    __shared__ unsigned sm[1024];
    int t = threadIdx.x;
    unsigned v = (t < nb) ? bsum[t] : 0u;
    sm[t] = v;
    __syncthreads();
    unsigned x = v;
    for (int o = 1; o < 1024; o <<= 1) {
        unsigned add = (t >= o) ? sm[t - o] : 0u;
        __syncthreads();
        x += add; sm[t] = x;
        __syncthreads();
    }
    if (t < nb) boff[t] = x - v;
}

__global__ __launch_bounds__(256) void scan3_kernel(unsigned* __restrict__ rp,
                                                    const unsigned* __restrict__ boff,
                                                    int N, int E) {
    int i = blockIdx.x * 256 + threadIdx.x;
    if (i < N) rp[i] = rp[i] + boff[blockIdx.x];
    if (i == 0) rp[N] = (unsigned)E;
}

// one packed 8B store per edge; no atomics
__global__ __launch_bounds__(256) void csr_scatter_kernel(
    const int* __restrict__ ei, const float* __restrict__ eattr,
    const unsigned* __restrict__ rp, const unsigned* __restrict__ rank,
    int2* __restrict__ eca, int E) {
    int e = blockIdx.x * 256 + threadIdx.x;
    if (e >= E) return;
    int s = ei[e], d = ei[E + e];
    unsigned p = rp[d] + rank[e];
    eca[p] = make_int2(s, __float_as_int(eattr[e]));
}

// ===== fused per-layer edge pipeline: 4 dst nodes per wave =================
__global__ __launch_bounds__(256) void gat_fused_kernel(
    const unsigned* __restrict__ rp, const int2* __restrict__ eca,
    const unsigned short* __restrict__ hw16,
    const float* __restrict__ a_s, const float* __restrict__ a_d,
    const float* __restrict__ c1, const float* __restrict__ c0,
    float* __restrict__ h, const float* __restrict__ bg,
    const float* __restrict__ g, const float* __restrict__ b, int N) {
    __shared__ float exl[4 * 272];
    __shared__ int srl[4 * 68];
    int t = blockIdx.x * blockDim.x + threadIdx.x;
    int lane = t & 63;
    int q = lane >> 4;
    int l = lane & 15;
    int hd = l >> 2;
    int sub = l & 3;
    int n = ((t >> 6) << 2) + q;
    int wslot = (threadIdx.x >> 6);
    float* myex = exl + wslot * 272 + 68 * q;
    int* mysrc = srl + wslot * 68 + 17 * q;

    bool nv = n < N;
    unsigned beg = nv ? rp[n] : 0u;
    int deg = nv ? (int)(rp[n + 1] - beg) : 0;

    float4 ad4 = nv ? *(const float4*)(a_d + ((size_t)n << 2)) : make_float4(0, 0, 0, 0);
    float4 C1 = *(const float4*)c1;
    float4 C0 = *(const float4*)c0;

    int md = deg;
    md = max(md, __shfl_xor(md, 16));
    md = max(md, __shfl_xor(md, 32));
    int chunks = (md + 15) >> 4;

    const unsigned* __restrict__ hwp = (const unsigned*)hw16;
    unsigned loff = (unsigned)(l << 1);

    float ssum = 0.f;
    float ac0 = 0.f, ac1 = 0.f, ac2 = 0.f, ac3 = 0.f;

    for (int k = 0; k < chunks; k++) {
        int i = (k << 4) + l;
        bool act = i < deg;
        int2 ce = act ? eca[beg + i] : make_int2(0, 0);
        int src = ce.x;
        float ea = __int_as_float(ce.y);
        float4 as4 = act ? *(const float4*)(a_s + ((size_t)src << 2))
                         : make_float4(0, 0, 0, 0);
        float s0 = as4.x + ad4.x + ea * C1.x + C0.x;
        float s1 = as4.y + ad4.y + ea * C1.y + C0.y;
        float s2 = as4.z + ad4.z + ea * C1.z + C0.z;
        float s3 = as4.w + ad4.w + ea * C1.w + C0.w;
        s0 = s0 >= 0.f ? s0 : 0.2f * s0;
        s1 = s1 >= 0.f ? s1 : 0.2f * s1;
        s2 = s2 >= 0.f ? s2 : 0.2f * s2;
        s3 = s3 >= 0.f ? s3 : 0.2f * s3;
        float e0 = act ? __expf(s0) : 0.f;
        float e1 = act ? __expf(s1) : 0.f;
        float e2 = act ? __expf(s2) : 0.f;
        float e3 = act ? __expf(s3) : 0.f;
        *(float4*)(myex + (l << 2)) = make_float4(e0, e1, e2, e3);
        mysrc[l] = act ? src : 0;

        float w0 = myex[(sub << 2) + hd];
        float w1 = myex[((sub + 4) << 2) + hd];
        float w2 = myex[((sub + 8) << 2) + hd];
        float w3 = myex[((sub + 12) << 2) + hd];
        float csum = (w0 + w1) + (w2 + w3);
        csum += __shfl_xor(csum, 1);
        csum += __shfl_xor(csum, 2);
        ssum += csum;

#pragma unroll
        for (int e = 0; e < 16; e++) {
            float w = myex[(e << 2) + hd];
            int so = mysrc[e];
            uint2 uu = *(const uint2*)(hwp + (((unsigned)so << 5) + loff));
            ac0 += w * __uint_as_float(uu.x << 16);
            ac1 += w * __uint_as_float(uu.x & 0xffff0000u);
            ac2 += w * __uint_as_float(uu.y << 16);
            ac3 += w * __uint_as_float(uu.y & 0xffff0000u);
        }
    }

    if (!nv) return;
    float inv = 1.f / (ssum + 1e-16f);
    float4 bg4 = *(const float4*)(bg + (l << 2));
    float4 hv4 = *(const float4*)(h + (size_t)n * HIDN + (l << 2));

    float a0 = ac0 * inv + bg4.x;
    float a1 = ac1 * inv + bg4.y;
    float a2 = ac2 * inv + bg4.z;
    float a3 = ac3 * inv + bg4.w;
    a0 = a0 > 0.f ? a0 : (__expf(a0) - 1.f);
    a1 = a1 > 0.f ? a1 : (__expf(a1) - 1.f);
    a2 = a2 > 0.f ? a2 : (__expf(a2) - 1.f);
    a3 = a3 > 0.f ? a3 : (__expf(a3) - 1.f);
    float v0 = hv4.x + a0, v1 = hv4.y + a1, v2 = hv4.z + a2, v3 = hv4.w + a3;

    float s = (v0 + v1) + (v2 + v3);
    float sq = (v0 * v0 + v1 * v1) + (v2 * v2 + v3 * v3);
#pragma unroll
    for (int o = 8; o > 0; o >>= 1) {
        s += __shfl_xor(s, o);
        sq += __shfl_xor(sq, o);
    }
    float mean = s * (1.f / 64.f);
    float var = sq * (1.f / 64.f) - mean * mean;
    float rr = rsqrtf(var + 1e-5f);
    float4 g4 = *(const float4*)(g + (l << 2));
    float4 b4 = *(const float4*)(b + (l << 2));
    float4 outv;
    outv.x = (v0 - mean) * rr * g4.x + b4.x;
    outv.y = (v1 - mean) * rr * g4.y + b4.y;
    outv.z = (v2 - mean) * rr * g4.z + b4.z;
    outv.w = (v3 - mean) * rr * g4.w + b4.w;
    *(float4*)(h + (size_t)n * HIDN + (l << 2)) = outv;
}

extern "C" void kernel_launch(void* const* d_in, const int* in_sizes, int n_in,
                              void* d_out, int out_size, void* d_ws, size_t ws_size,
                              hipStream_t stream) {
    const float* x      = (const float*)d_in[0];
    const int*   ei     = (const int*)d_in[1];
    const float* eattr  = (const float*)d_in[2];
    const float* w_ne1  = (const float*)d_in[3];
    const float* b_ne1  = (const float*)d_in[4];
    const float* w_ne2  = (const float*)d_in[5];
    const float* b_ne2  = (const float*)d_in[6];
    const float* w_ee   = (const float*)d_in[7];
    const float* b_ee   = (const float*)d_in[8];
    const float* w_gat  = (const float*)d_in[9];
    const float* w_eg   = (const float*)d_in[10];
    const float* att_src= (const float*)d_in[11];
    const float* att_dst= (const float*)d_in[12];
    const float* att_edge=(const float*)d_in[13];
    const float* b_gat  = (const float*)d_in[14];
    const float* ln_g   = (const float*)d_in[15];
    const float* ln_b   = (const float*)d_in[16];
    const float* w_out  = (const float*)d_in[17];
    const float* b_out  = (const float*)d_in[18];

    const int N = in_sizes[0] / NIN;
    const int E = in_sizes[2];

    // -------- workspace layout --------
    float* ws   = (float*)d_ws;
    float* h    = ws;                                   // N*64
    float* hid  = h + (size_t)N * 64;                   // N*64
    unsigned short* hw16 = (unsigned short*)(hid + (size_t)N * 64);  // N*64 u16
    float* a_s  = (float*)(hw16 + (size_t)N * 64);      // N*4
    float* a_d  = a_s + (size_t)N * 4;                  // N*4
    float* c1   = a_d + (size_t)N * 4;                  // 12
    float* c0   = c1 + 12;                              // 12
    int2*  eca  = (int2*)(c0 + 12);                     // E int2
    unsigned* rank = (unsigned*)(eca + (size_t)E);      // E
    unsigned* deg  = rank + (size_t)E;                  // N<<DEGPAD (line-padded)
    unsigned* rp   = deg + ((size_t)N << DEGPAD);       // N+1
    unsigned* bsum = rp + (size_t)N + 1;                // <=1024
    unsigned* boff = bsum + 1024;                       // <=1024

    dim3 blk(256);
    int nodeWaveBlocks = (int)(((size_t)N * 64 + 255) / 256);
    int quadBlocks = (int)(((size_t)((N + 3) / 4) * 64 + 255) / 256);
    int edgeBlocks = (E + 255) / 256;
    int nodeBlocks = (N + 255) / 256;
    int mmBlocks = 2048;    // 8192 waves, grid-stride over nodes

    // -------- CSR build (rank from hist atomic; scatter atomic-free) -------
    hipMemsetAsync(deg, 0, ((size_t)N << DEGPAD) * sizeof(unsigned), stream);
    hist_kernel<<<edgeBlocks, blk, 0, stream>>>(ei, deg, rank, E);
    scan1_kernel<<<nodeBlocks, blk, 0, stream>>>(deg, rp, bsum, N);
    scan2_kernel<<<1, 1024, 0, stream>>>(bsum, boff, nodeBlocks);
    scan3_kernel<<<nodeBlocks, blk, 0, stream>>>(rp, boff, N, E);
    csr_scatter_kernel<<<edgeBlocks, blk, 0, stream>>>(ei, eattr, rp, rank, eca, E);

    consts_kernel<<<1, 64, 0, stream>>>(w_ee, b_ee, w_eg, att_edge, c1, c0);

    // -------- encoder: hid = relu(x@w1+b1); h = hid@w2+b2 --------
    encode1_kernel<<<nodeWaveBlocks, blk, 0, stream>>>(x, w_ne1, b_ne1, hid, N);
    mm64_plain_kernel<<<mmBlocks, blk, 0, stream>>>(hid, w_ne2, b_ne2, h, N);

    // layer-0 transform
    mm64_attn_kernel<<<mmBlocks, blk, 0, stream>>>(
        h, w_gat, att_src, att_dst, hw16, a_s, a_d, N);

    for (int l = 0; l < 3; l++) {
        gat_fused_kernel<<<quadBlocks, blk, 0, stream>>>(
            rp, eca, hw16, a_s, a_d, c1 + l * 4, c0 + l * 4,
            h, b_gat + l * 64, ln_g + l * 64, ln_b + l * 64, N);
        if (l < 2) {
            mm64_attn_kernel<<<mmBlocks, blk, 0, stream>>>(
                h, w_gat + (size_t)(l + 1) * 4096,
                att_src + (l + 1) * 64, att_dst + (l + 1) * 64,
                hw16, a_s, a_d, N);
        }
    }
    // -------- output projection --------
    mm64_plain_kernel<<<mmBlocks, blk, 0, stream>>>(h, w_out, b_out, (float*)d_out, N);
}